// Round 4
// baseline (176.029 us; speedup 1.0000x reference)
//
#include <hip/hip_runtime.h>

#define B_ 16
#define T_ 400
#define NH_ 100
#define NB_ 65
#define BLK_ 160
#define SR_ 16000
#define N_ 64000           // T_*BLK_
#define REV_ 16000
#define KPAD_ 16128        // front zero pad of signal
#define KTOT_ 80128        // KPAD_ + N_
#define NT_ 1038           // Toeplitz frag table entries (tB = 1008 - 2c + 14 + m)
#define KSPLIT_ 8
#define STEPS_ 64          // 512 chunks / KSPLIT_
#define M_ 16              // m-tiles per wave (256 outputs)
#define NWG_ 250

typedef __attribute__((ext_vector_type(8))) short bf16x8;
typedef __attribute__((ext_vector_type(4))) float f32x4;

static __device__ __forceinline__ unsigned short f2bf(float f) {
  unsigned u = __float_as_uint(f);
  unsigned r = (u + 0x7fffu + ((u >> 16) & 1u)) >> 16;
  return (unsigned short)r;
}
static __device__ __forceinline__ float bf2f(unsigned short h) {
  return __uint_as_float(((unsigned)h) << 16);
}

// ---------------- K1: fp64 prefix of per-block phase increments (REVOLUTIONS) ----------------
__global__ __launch_bounds__(512) void k_prefix(const float* __restrict__ pitch,
                                                double* __restrict__ Pv,
                                                double* __restrict__ Xv) {
  __shared__ double s[512];
  const int b = blockIdx.x, t = threadIdx.x;
  double x = 0.0;
  if (t < T_) x = (double)pitch[b * T_ + t] * (1.0 / (double)SR_);
  s[t] = x;
  __syncthreads();
  for (int off = 1; off < 512; off <<= 1) {
    double v = (t >= off) ? s[t - off] : 0.0;
    __syncthreads();
    s[t] += v;
    __syncthreads();
  }
  if (t < T_) {
    Xv[b * T_ + t] = x;
    Pv[b * T_ + t] = (s[t] - x) * 160.0;
  }
}

// ---------------- K2: per-(b,t) harmonic synth + filtered noise -> packed bf16 hi/lo ----------------
__global__ __launch_bounds__(160) void k_synth(
    const float* __restrict__ pitch, const float* __restrict__ tamp,
    const float* __restrict__ harmo, const float* __restrict__ nfilt,
    const float* __restrict__ noise, const double* __restrict__ Pv,
    const double* __restrict__ Xv, unsigned short* __restrict__ PH,
    unsigned short* __restrict__ PL) {
  const int bt = blockIdx.x, b = bt / T_, t = bt - b * T_;
  const int tid = threadIdx.x;
  __shared__ float amp[NH_], sbase[NH_], sstep[NH_];
  __shared__ float a_s[NB_], ctab[128], ir_s[128], imp_s[BLK_], noi_s[BLK_], red[128];

  const float pv = pitch[b * T_ + t];
  if (tid < 128) ctab[tid] = cosf((float)tid * 0.049087385212340526f);  // 2pi/128
  if (tid < NB_) a_s[tid] = nfilt[bt * NB_ + tid];
  noi_s[tid] = noise[bt * BLK_ + tid];
  if (tid < NH_) {
    float ha = harmo[(b * NH_ + tid) * T_ + t];
    float aa = (pv * (float)(tid + 1) < 8000.0f ? 1.0f : 0.0f) + 1e-4f;
    amp[tid] = ha * aa;
  }
  __syncthreads();
  if (tid < 128) {
    float sum = 0.f;
    for (int k = 1; k < 64; ++k) sum = fmaf(a_s[k], ctab[(k * tid) & 127], sum);
    float v = a_s[0] + ((tid & 1) ? -a_s[64] : a_s[64]) + 2.f * sum;
    ir_s[tid] = v * (1.0f / 128.0f);
    red[tid] = (tid < NH_) ? amp[tid] : 0.f;
  }
  __syncthreads();
  for (int off = 64; off >= 1; off >>= 1) {
    if (tid < off) red[tid] += red[tid + off];
    __syncthreads();
  }
  const float scale = tamp[b * T_ + t] / red[0];
  if (tid < NH_) {
    amp[tid] *= scale;
    const double h = (double)(tid + 1);
    double vb = h * Pv[b * T_ + t];
    vb -= floor(vb);
    sbase[tid] = (float)vb;
    double vs = h * Xv[b * T_ + t];
    vs -= floor(vs);
    sstep[tid] = (float)vs;
  }
  {
    float v;
    if (tid < 64)      v = (0.5f - 0.5f * ctab[tid + 64]) * ir_s[tid];
    else if (tid < 96) v = 0.f;
    else               v = (0.5f - 0.5f * ctab[tid - 96]) * ir_s[tid - 32];
    imp_s[tid] = v;
  }
  __syncthreads();
  float nf = 0.f;
  for (int j = 0; j <= tid; ++j) nf = fmaf(noi_s[j], imp_s[tid - j], nf);
  const float fi = (float)(tid + 1);
  float acc = 0.f;
#pragma unroll 4
  for (int h = 0; h < NH_; ++h) {
    float ph = fmaf(fi, sstep[h], sbase[h]);
    ph = __builtin_amdgcn_fractf(ph);
    acc = fmaf(amp[h], __builtin_amdgcn_sinf(ph), acc);
  }
  const float v = acc + nf;
  const unsigned k = (unsigned)(KPAD_ + t * BLK_ + tid);
  const unsigned off = ((k >> 3) << 7) + ((unsigned)b << 3) + (k & 7u);
  const unsigned short h = f2bf(v);
  PH[off] = h;
  PL[off] = f2bf(v - bf2f(h));
}

// ---------------- K3: Toeplitz A-fragment table (hi/lo bf16) + signal front-pad zero ----------------
// FRAG[t][lane][j] = imp[(t-14)*16 + (lane&15) - 8*(lane>>4) - j]
__global__ __launch_bounds__(512) void k_fragbuild(const float* __restrict__ rn,
                                                   const float* __restrict__ dec,
                                                   const float* __restrict__ wet,
                                                   unsigned short* __restrict__ FH,
                                                   unsigned short* __restrict__ FL,
                                                   unsigned short* __restrict__ PH,
                                                   unsigned short* __restrict__ PL) {
  const int t = blockIdx.x, tid = threadIdx.x;
  // fold in: zero the KPAD_ front pads of PH and PL (32256 16B-chunks each)
  const int gid = t * 512 + tid;
  if (gid < 32256) {
    ((f32x4*)PH)[gid] = (f32x4){0.f, 0.f, 0.f, 0.f};
  } else if (gid < 64512) {
    ((f32x4*)PL)[gid - 32256] = (f32x4){0.f, 0.f, 0.f, 0.f};
  }
  const int lane = tid >> 3, j = tid & 7;
  const int idx = (t - 14) * 16 + (lane & 15) - ((lane >> 4) << 3) - j;
  float v = 0.f;
  if (idx == 0) {
    v = 1.0f;
  } else if (idx > 0 && idx < REV_) {
    const float a = log1pf(expf(-dec[0]));
    const float sg = 1.f / (1.f + expf(-wet[0]));
    v = rn[idx] * expf(-a * ((float)idx / (float)SR_) * 500.0f) * sg;
  }
  const unsigned short h = f2bf(v);
  FH[t * 512 + tid] = h;
  FL[t * 512 + tid] = f2bf(v - bf2f(h));
}

// ---------------- K4: reverb as Toeplitz MFMA GEMM ----------------
// 256 outputs per block, 8 waves = 8 K-splits, ring of 16 A-frags, LDS 2-stage reduce.
static __device__ __forceinline__ f32x4 mfma_bf16(bf16x8 a, bf16x8 b, f32x4 c) {
  return __builtin_amdgcn_mfma_f32_16x16x32_bf16(a, b, c, 0, 0, 0);
}

template <int U, bool PF>
__device__ __forceinline__ void conv_step(bf16x8 (&Rh)[M_], bf16x8 (&Rl)[M_], f32x4 (&acc)[M_],
                                          bf16x8& bhi, bf16x8& blo,
                                          const bf16x8* __restrict__ ph,
                                          const bf16x8* __restrict__ pl,
                                          const bf16x8* __restrict__ fh,
                                          const bf16x8* __restrict__ fl,
                                          int& kcur, int& tcur) {
  bf16x8 nbh, nbl, na0h, na1h, na0l, na1l;
  if (PF) {
    kcur += 64;              // +32 samples = +64 bf16x8 units
    nbh = ph[kcur]; nbl = pl[kcur];
    tcur -= 2;
    na0h = fh[tcur * 64]; na1h = fh[(tcur + 1) * 64];
    na0l = fl[tcur * 64]; na1l = fl[(tcur + 1) * 64];
  }
#pragma unroll
  for (int m = 0; m < M_; ++m) {
    const int sl = (m - 2 * U) & (M_ - 1);
    acc[m] = mfma_bf16(Rh[sl], bhi, acc[m]);
    acc[m] = mfma_bf16(Rh[sl], blo, acc[m]);
    acc[m] = mfma_bf16(Rl[sl], bhi, acc[m]);
  }
  if (PF) {
    Rh[(M_ - 2 - 2 * U) & (M_ - 1)] = na0h; Rh[(M_ - 1 - 2 * U) & (M_ - 1)] = na1h;
    Rl[(M_ - 2 - 2 * U) & (M_ - 1)] = na0l; Rl[(M_ - 1 - 2 * U) & (M_ - 1)] = na1l;
    bhi = nbh; blo = nbl;
  }
}

__global__ __launch_bounds__(512, 2) void k_mconv(const bf16x8* __restrict__ FH,
                                                  const bf16x8* __restrict__ FL,
                                                  const bf16x8* __restrict__ PH,
                                                  const bf16x8* __restrict__ PL,
                                                  float* __restrict__ out) {
  const int tid = threadIdx.x;
  const int s = tid >> 6, lane = tid & 63;
  int w = blockIdx.x;
  {  // bijective XCD swizzle, nwg=250 (q=31, r=2)
    const int q = NWG_ / 8, r = NWG_ % 8;
    const int xcd = w & 7, o = w >> 3;
    w = (xcd < r ? xcd * (q + 1) : r * (q + 1) + (xcd - r) * q) + o;
  }
  const int Q0 = w << 8;                    // 256 outputs per tile
  const int T0 = 1022 - 128 * s;            // frag-table index at local step 0, m=0

  const bf16x8* fh = FH + lane;
  const bf16x8* fl = FL + lane;
  bf16x8 Rh[M_], Rl[M_];
#pragma unroll
  for (int m = 0; m < M_; ++m) {
    Rh[m] = fh[(T0 + m) * 64];
    Rl[m] = fl[(T0 + m) * 64];
  }
  f32x4 acc[M_];
#pragma unroll
  for (int m = 0; m < M_; ++m) acc[m] = (f32x4){0.f, 0.f, 0.f, 0.f};

  const bf16x8* ph = PH + ((lane >> 4) << 4) + (lane & 15);
  const bf16x8* pl = PL + ((lane >> 4) << 4) + (lane & 15);

  int kcur = (Q0 + 2048 * s) << 1;          // unit index of chunk base
  int tcur = T0;
  bf16x8 bhi = ph[kcur], blo = pl[kcur];

  for (int ii = 0; ii < 7; ++ii) {          // 56 steps
    conv_step<0, true>(Rh, Rl, acc, bhi, blo, ph, pl, fh, fl, kcur, tcur);
    conv_step<1, true>(Rh, Rl, acc, bhi, blo, ph, pl, fh, fl, kcur, tcur);
    conv_step<2, true>(Rh, Rl, acc, bhi, blo, ph, pl, fh, fl, kcur, tcur);
    conv_step<3, true>(Rh, Rl, acc, bhi, blo, ph, pl, fh, fl, kcur, tcur);
    conv_step<4, true>(Rh, Rl, acc, bhi, blo, ph, pl, fh, fl, kcur, tcur);
    conv_step<5, true>(Rh, Rl, acc, bhi, blo, ph, pl, fh, fl, kcur, tcur);
    conv_step<6, true>(Rh, Rl, acc, bhi, blo, ph, pl, fh, fl, kcur, tcur);
    conv_step<7, true>(Rh, Rl, acc, bhi, blo, ph, pl, fh, fl, kcur, tcur);
  }
  conv_step<0, true>(Rh, Rl, acc, bhi, blo, ph, pl, fh, fl, kcur, tcur);   // 57..64
  conv_step<1, true>(Rh, Rl, acc, bhi, blo, ph, pl, fh, fl, kcur, tcur);
  conv_step<2, true>(Rh, Rl, acc, bhi, blo, ph, pl, fh, fl, kcur, tcur);
  conv_step<3, true>(Rh, Rl, acc, bhi, blo, ph, pl, fh, fl, kcur, tcur);
  conv_step<4, true>(Rh, Rl, acc, bhi, blo, ph, pl, fh, fl, kcur, tcur);
  conv_step<5, true>(Rh, Rl, acc, bhi, blo, ph, pl, fh, fl, kcur, tcur);
  conv_step<6, true>(Rh, Rl, acc, bhi, blo, ph, pl, fh, fl, kcur, tcur);
  conv_step<7, false>(Rh, Rl, acc, bhi, blo, ph, pl, fh, fl, kcur, tcur);

  // two-stage cross-wave (K-split) reduction in LDS, then plain coalesced stores
  __shared__ f32x4 part[4][M_][64];
  if (s < 4) {
#pragma unroll
    for (int m = 0; m < M_; ++m) part[s][m][lane] = acc[m];
  }
  __syncthreads();
  if (s >= 4) {
#pragma unroll
    for (int m = 0; m < M_; ++m) part[s - 4][m][lane] += acc[m];
  }
  __syncthreads();
#pragma unroll
  for (int half = 0; half < 2; ++half) {
    const int it = tid + (half << 9);
    const int m = it >> 6, ln = it & 63;
    f32x4 v = part[0][m][ln];
    v += part[1][m][ln];
    v += part[2][m][ln];
    v += part[3][m][ln];
    const int b = ln & 15, g = ln >> 4;
    *(f32x4*)(out + (size_t)b * N_ + Q0 + (m << 4) + (g << 2)) = v;
  }
}

extern "C" void kernel_launch(void* const* d_in, const int* in_sizes, int n_in,
                              void* d_out, int out_size, void* d_ws, size_t ws_size,
                              hipStream_t stream) {
  const float* pitch = (const float*)d_in[0];
  const float* tamp  = (const float*)d_in[1];
  const float* harmo = (const float*)d_in[2];
  const float* nfilt = (const float*)d_in[3];
  const float* noise = (const float*)d_in[4];
  const float* rn    = (const float*)d_in[5];
  const float* dec   = (const float*)d_in[6];
  const float* wet   = (const float*)d_in[7];

  char* ws = (char*)d_ws;
  size_t off = 0;
  unsigned short* PH = (unsigned short*)(ws + off); off += (size_t)KTOT_ * 16 * 2;  // 2.56 MB
  unsigned short* PL = (unsigned short*)(ws + off); off += (size_t)KTOT_ * 16 * 2;
  unsigned short* FH = (unsigned short*)(ws + off); off += (size_t)NT_ * 512 * 2;   // 1.06 MB
  unsigned short* FL = (unsigned short*)(ws + off); off += (size_t)NT_ * 512 * 2;
  double* Pv = (double*)(ws + off);           off += (size_t)B_ * T_ * 8;
  double* Xv = (double*)(ws + off);           off += (size_t)B_ * T_ * 8;
  float* out = (float*)d_out;

  k_prefix<<<dim3(B_), dim3(512), 0, stream>>>(pitch, Pv, Xv);
  k_synth<<<dim3(B_ * T_), dim3(160), 0, stream>>>(pitch, tamp, harmo, nfilt, noise, Pv, Xv, PH, PL);
  k_fragbuild<<<dim3(NT_), dim3(512), 0, stream>>>(rn, dec, wet, FH, FL, PH, PL);
  k_mconv<<<dim3(NWG_), dim3(512), 0, stream>>>(
      (const bf16x8*)FH, (const bf16x8*)FL, (const bf16x8*)PH, (const bf16x8*)PL, out);
}

// Round 5
// 86.151 us; speedup vs baseline: 2.0433x; 2.0433x over previous
//
#include <hip/hip_runtime.h>

#define B_ 16
#define T_ 400
#define NH_ 100
#define NB_ 65
#define BLK_ 160
#define SR_ 16000
#define N_ 64000           // T_*BLK_
#define REV_ 16000
#define KPAD_ 16128        // front zero pad of signal
#define KTOT_ 80128        // KPAD_ + N_
#define NT_ 1022           // Toeplitz frag table entries, t in [0,1021]
#define KSPLIT_ 8
#define STEPS_ 63          // 504 chunks / KSPLIT_
#define M_ 8               // m-tiles per wave (128 outputs)
#define NWG_ 500

typedef __attribute__((ext_vector_type(8))) _Float16 f16x8;
typedef __attribute__((ext_vector_type(4))) float f32x4;

// ---------------- K1: fp64 prefix of per-block phase increments (REVOLUTIONS) ----------------
__global__ __launch_bounds__(512) void k_prefix(const float* __restrict__ pitch,
                                                double* __restrict__ Pv,
                                                double* __restrict__ Xv) {
  __shared__ double s[512];
  const int b = blockIdx.x, t = threadIdx.x;
  double x = 0.0;
  if (t < T_) x = (double)pitch[b * T_ + t] * (1.0 / (double)SR_);
  s[t] = x;
  __syncthreads();
  for (int off = 1; off < 512; off <<= 1) {
    double v = (t >= off) ? s[t - off] : 0.0;
    __syncthreads();
    s[t] += v;
    __syncthreads();
  }
  if (t < T_) {
    Xv[b * T_ + t] = x;
    Pv[b * T_ + t] = (s[t] - x) * 160.0;
  }
}

// ---------------- K2: per-(b,t) harmonic synth + filtered noise -> packed fp16 ----------------
__global__ __launch_bounds__(160) void k_synth(
    const float* __restrict__ pitch, const float* __restrict__ tamp,
    const float* __restrict__ harmo, const float* __restrict__ nfilt,
    const float* __restrict__ noise, const double* __restrict__ Pv,
    const double* __restrict__ Xv, _Float16* __restrict__ PH) {
  const int bt = blockIdx.x, b = bt / T_, t = bt - b * T_;
  const int tid = threadIdx.x;
  __shared__ float amp[NH_], sbase[NH_], sstep[NH_];
  __shared__ float a_s[NB_], ctab[128], ir_s[128], imp_s[BLK_], noi_s[BLK_], red[128];

  const float pv = pitch[b * T_ + t];
  if (tid < 128) ctab[tid] = cosf((float)tid * 0.049087385212340526f);  // 2pi/128
  if (tid < NB_) a_s[tid] = nfilt[bt * NB_ + tid];
  noi_s[tid] = noise[bt * BLK_ + tid];
  if (tid < NH_) {
    float ha = harmo[(b * NH_ + tid) * T_ + t];
    float aa = (pv * (float)(tid + 1) < 8000.0f ? 1.0f : 0.0f) + 1e-4f;
    amp[tid] = ha * aa;
  }
  __syncthreads();
  if (tid < 128) {
    float sum = 0.f;
    for (int k = 1; k < 64; ++k) sum = fmaf(a_s[k], ctab[(k * tid) & 127], sum);
    float v = a_s[0] + ((tid & 1) ? -a_s[64] : a_s[64]) + 2.f * sum;
    ir_s[tid] = v * (1.0f / 128.0f);
    red[tid] = (tid < NH_) ? amp[tid] : 0.f;
  }
  __syncthreads();
  for (int off = 64; off >= 1; off >>= 1) {
    if (tid < off) red[tid] += red[tid + off];
    __syncthreads();
  }
  const float scale = tamp[b * T_ + t] / red[0];
  if (tid < NH_) {
    amp[tid] *= scale;
    const double h = (double)(tid + 1);
    double vb = h * Pv[b * T_ + t];
    vb -= floor(vb);
    sbase[tid] = (float)vb;
    double vs = h * Xv[b * T_ + t];
    vs -= floor(vs);
    sstep[tid] = (float)vs;
  }
  {
    float v;
    if (tid < 64)      v = (0.5f - 0.5f * ctab[tid + 64]) * ir_s[tid];
    else if (tid < 96) v = 0.f;
    else               v = (0.5f - 0.5f * ctab[tid - 96]) * ir_s[tid - 32];
    imp_s[tid] = v;
  }
  __syncthreads();
  float nf = 0.f;
  for (int j = 0; j <= tid; ++j) nf = fmaf(noi_s[j], imp_s[tid - j], nf);
  const float fi = (float)(tid + 1);
  float acc = 0.f;
#pragma unroll 4
  for (int h = 0; h < NH_; ++h) {
    float ph = fmaf(fi, sstep[h], sbase[h]);
    ph = __builtin_amdgcn_fractf(ph);
    acc = fmaf(amp[h], __builtin_amdgcn_sinf(ph), acc);
  }
  const float v = acc + nf;
  const unsigned k = (unsigned)(KPAD_ + t * BLK_ + tid);
  const unsigned off = ((k >> 3) << 7) + ((unsigned)b << 3) + (k & 7u);
  PH[off] = (_Float16)v;
}

// ---------------- K3: Toeplitz A-fragment table (fp16) + signal front-pad zero ----------------
// FRAG[t][lane][j] = imp[(t-14)*16 + (lane&15) - 8*(lane>>4) - j]
__global__ __launch_bounds__(512) void k_fragbuild(const float* __restrict__ rn,
                                                   const float* __restrict__ dec,
                                                   const float* __restrict__ wet,
                                                   _Float16* __restrict__ FH,
                                                   _Float16* __restrict__ PH) {
  const int t = blockIdx.x, tid = threadIdx.x;
  // fold in: zero the KPAD_ front pad of PH (32256 16B-chunks)
  const int gid = t * 512 + tid;
  if (gid < 32256) ((f32x4*)PH)[gid] = (f32x4){0.f, 0.f, 0.f, 0.f};
  const int lane = tid >> 3, j = tid & 7;
  const int idx = (t - 14) * 16 + (lane & 15) - ((lane >> 4) << 3) - j;
  float v = 0.f;
  if (idx == 0) {
    v = 1.0f;
  } else if (idx > 0 && idx < REV_) {
    const float a = log1pf(expf(-dec[0]));
    const float sg = 1.f / (1.f + expf(-wet[0]));
    v = rn[idx] * expf(-a * ((float)idx / (float)SR_) * 500.0f) * sg;
  }
  FH[t * 512 + tid] = (_Float16)v;
}

// ---------------- K4: reverb as Toeplitz MFMA GEMM (single fp16 product) ----------------
static __device__ __forceinline__ f32x4 mfma_f16(f16x8 a, f16x8 b, f32x4 c) {
  return __builtin_amdgcn_mfma_f32_16x16x32_f16(a, b, c, 0, 0, 0);
}

template <int U, bool PF>
__device__ __forceinline__ void conv_step(f16x8 (&Rh)[M_], f32x4 (&acc)[M_], f16x8& bhi,
                                          const f16x8* __restrict__ ph,
                                          const f16x8* __restrict__ fh,
                                          int& kcur, int& tcur) {
  f16x8 nbh, na0, na1;
  if (PF) {
    kcur += 64;              // +32 samples = +64 f16x8 units
    nbh = ph[kcur];
    tcur -= 2;
    na0 = fh[tcur * 64];
    na1 = fh[(tcur + 1) * 64];
  }
#pragma unroll
  for (int m = 0; m < M_; ++m) {
    const int sl = (m - 2 * U) & (M_ - 1);
    acc[m] = mfma_f16(Rh[sl], bhi, acc[m]);
  }
  if (PF) {
    Rh[(M_ - 2 - 2 * U) & (M_ - 1)] = na0;
    Rh[(M_ - 1 - 2 * U) & (M_ - 1)] = na1;
    bhi = nbh;
  }
}

__global__ __launch_bounds__(512) void k_mconv(const f16x8* __restrict__ FH,
                                               const f16x8* __restrict__ PH,
                                               float* __restrict__ out) {
  const int tid = threadIdx.x;
  const int s = tid >> 6, lane = tid & 63;
  int w = blockIdx.x;
  {  // bijective XCD swizzle, nwg=500 (q=62, r=4)
    const int q = NWG_ / 8, r = NWG_ % 8;
    const int xcd = w & 7, o = w >> 3;
    w = (xcd < r ? xcd * (q + 1) : r * (q + 1) + (xcd - r) * q) + o;
  }
  const int Q0 = w << 7;                    // 128 outputs per tile
  const int T0 = 1014 - 126 * s;            // frag-table index at step 0, m=0

  const f16x8* fh = FH + lane;
  f16x8 Rh[M_];
#pragma unroll
  for (int m = 0; m < M_; ++m) Rh[m] = fh[(T0 + m) * 64];
  f32x4 acc[M_];
#pragma unroll
  for (int m = 0; m < M_; ++m) acc[m] = (f32x4){0.f, 0.f, 0.f, 0.f};

  const f16x8* ph = PH + ((lane >> 4) << 4) + (lane & 15);
  int kcur = (Q0 + 128 + 2016 * s) << 1;    // unit index of chunk base
  int tcur = T0;
  f16x8 bhi = ph[kcur];

  for (int ii = 0; ii < 15; ++ii) {         // 60 steps
    conv_step<0, true>(Rh, acc, bhi, ph, fh, kcur, tcur);
    conv_step<1, true>(Rh, acc, bhi, ph, fh, kcur, tcur);
    conv_step<2, true>(Rh, acc, bhi, ph, fh, kcur, tcur);
    conv_step<3, true>(Rh, acc, bhi, ph, fh, kcur, tcur);
  }
  conv_step<0, true>(Rh, acc, bhi, ph, fh, kcur, tcur);    // 61
  conv_step<1, true>(Rh, acc, bhi, ph, fh, kcur, tcur);    // 62
  conv_step<2, false>(Rh, acc, bhi, ph, fh, kcur, tcur);   // 63

  // two-stage cross-wave (K-split) reduction in LDS, then coalesced stores
  __shared__ f32x4 part[4][M_][64];
  if (s < 4) {
#pragma unroll
    for (int m = 0; m < M_; ++m) part[s][m][lane] = acc[m];
  }
  __syncthreads();
  if (s >= 4) {
#pragma unroll
    for (int m = 0; m < M_; ++m) part[s - 4][m][lane] += acc[m];
  }
  __syncthreads();
  {
    const int m = tid >> 6, ln = tid & 63;
    f32x4 v = part[0][m][ln];
    v += part[1][m][ln];
    v += part[2][m][ln];
    v += part[3][m][ln];
    const int b = ln & 15, g = ln >> 4;
    *(f32x4*)(out + (size_t)b * N_ + Q0 + (m << 4) + (g << 2)) = v;
  }
}

extern "C" void kernel_launch(void* const* d_in, const int* in_sizes, int n_in,
                              void* d_out, int out_size, void* d_ws, size_t ws_size,
                              hipStream_t stream) {
  const float* pitch = (const float*)d_in[0];
  const float* tamp  = (const float*)d_in[1];
  const float* harmo = (const float*)d_in[2];
  const float* nfilt = (const float*)d_in[3];
  const float* noise = (const float*)d_in[4];
  const float* rn    = (const float*)d_in[5];
  const float* dec   = (const float*)d_in[6];
  const float* wet   = (const float*)d_in[7];

  char* ws = (char*)d_ws;
  size_t off = 0;
  _Float16* PH = (_Float16*)(ws + off); off += (size_t)KTOT_ * 16 * 2;   // 2.56 MB
  _Float16* FH = (_Float16*)(ws + off); off += (size_t)NT_ * 512 * 2;    // 1.05 MB
  double* Pv = (double*)(ws + off);     off += (size_t)B_ * T_ * 8;
  double* Xv = (double*)(ws + off);     off += (size_t)B_ * T_ * 8;
  float* out = (float*)d_out;

  k_prefix<<<dim3(B_), dim3(512), 0, stream>>>(pitch, Pv, Xv);
  k_synth<<<dim3(B_ * T_), dim3(160), 0, stream>>>(pitch, tamp, harmo, nfilt, noise, Pv, Xv, PH);
  k_fragbuild<<<dim3(NT_), dim3(512), 0, stream>>>(rn, dec, wet, FH, PH);
  k_mconv<<<dim3(NWG_), dim3(512), 0, stream>>>((const f16x8*)FH, (const f16x8*)PH, out);
}

// Round 6
// 73.698 us; speedup vs baseline: 2.3885x; 1.1690x over previous
//
#include <hip/hip_runtime.h>

#define B_ 16
#define T_ 400
#define NH_ 100
#define NB_ 65
#define BLK_ 160
#define SR_ 16000
#define N_ 64000           // T_*BLK_
#define REV_ 16000
#define KPAD_ 16128        // front zero pad of signal
#define KTOT_ 80128        // KPAD_ + N_
#define NT_ 1022           // Toeplitz frag table entries, t in [0,1021]
#define KSPLIT_ 8
#define STEPS_ 63          // 504 chunks / KSPLIT_
#define M_ 8               // m-tiles per wave (128 outputs)
#define NWG_ 500

typedef __attribute__((ext_vector_type(8))) _Float16 f16x8;
typedef __attribute__((ext_vector_type(2))) _Float16 f16x2;
typedef __attribute__((ext_vector_type(4))) float f32x4;

// complex rotation: (c,s) *= (c1,s1)
#define ROT(c, s, c1, s1)                                   \
  {                                                         \
    float _t = (c) * (s1);                                  \
    float _u = (s) * (s1);                                  \
    float _ns = fmaf((s), (c1), _t);                        \
    (c) = fmaf((c), (c1), -_u);                             \
    (s) = _ns;                                              \
  }

static __device__ __forceinline__ float dot2f(f16x2 a, f16x2 b, float c) {
#if __has_builtin(__builtin_amdgcn_fdot2)
  return __builtin_amdgcn_fdot2(a, b, c, false);
#else
  return fmaf((float)a[0], (float)b[0], fmaf((float)a[1], (float)b[1], c));
#endif
}

// ---------------- K1: fp64 prefix of per-block phase increments (REVOLUTIONS) ----------------
__global__ __launch_bounds__(512) void k_prefix(const float* __restrict__ pitch,
                                                double* __restrict__ Pv,
                                                double* __restrict__ Xv) {
  __shared__ double s[512];
  const int b = blockIdx.x, t = threadIdx.x;
  double x = 0.0;
  if (t < T_) x = (double)pitch[b * T_ + t] * (1.0 / (double)SR_);
  s[t] = x;
  __syncthreads();
  for (int off = 1; off < 512; off <<= 1) {
    double v = (t >= off) ? s[t - off] : 0.0;
    __syncthreads();
    s[t] += v;
    __syncthreads();
  }
  if (t < T_) {
    Xv[b * T_ + t] = x;
    Pv[b * T_ + t] = (s[t] - x) * 160.0;
  }
}

// ---------------- K2: per-(b,t) harmonic synth + filtered noise -> packed fp16 ----------------
__global__ __launch_bounds__(160) void k_synth(
    const float* __restrict__ pitch, const float* __restrict__ tamp,
    const float* __restrict__ harmo, const float* __restrict__ nfilt,
    const float* __restrict__ noise, const double* __restrict__ Pv,
    const double* __restrict__ Xv, _Float16* __restrict__ PH) {
  const int bt = blockIdx.x, b = bt / T_, t = bt - b * T_;
  const int tid = threadIdx.x;
  __shared__ __align__(16) float amp[104];
  __shared__ __align__(16) float a_s[NB_ + 3];
  __shared__ __align__(16) float ir_s[128];
  __shared__ __align__(16) _Float16 C0[320];      // noi_pad (160 zeros + noise)
  __shared__ __align__(16) _Float16 C1[320];      // shifted copy: C1[x] = noi_pad[x+1]
  __shared__ __align__(16) _Float16 imp_sw[128];  // [0..63] segA, [64..127] segB, pair-swapped
  __shared__ float red_s;

  const float pv = pitch[b * T_ + t];
  // n_valid: largest h (1-based) with fp32(h*pv) < 8000, capped at 100
  int nv = (int)(8000.0f / pv);
  if (nv > NH_) nv = NH_;
  while (nv < NH_ && (float)(nv + 1) * pv < 8000.0f) ++nv;
  while (nv > 0 && (float)nv * pv >= 8000.0f) --nv;

  // ---- phase A: loads/staging ----
  if (tid < NB_) a_s[tid] = nfilt[bt * NB_ + tid];
  {
    const _Float16 nh = (_Float16)noise[bt * BLK_ + tid];
    C0[160 + tid] = nh;
    C1[159 + tid] = nh;
    C0[tid] = (_Float16)0.f;
    if (tid < 159) C1[tid] = (_Float16)0.f;
  }
  if (tid < NH_) {
    const float ha = harmo[(b * NH_ + tid) * T_ + t];
    const float aa = (pv * (float)(tid + 1) < 8000.0f ? 1.0f : 0.0f) + 1e-4f;
    amp[tid] = ha * aa;
  } else if (tid < 104) {
    amp[tid] = 0.f;
  }
  __syncthreads();  // B1

  // ---- phase B: 128-pt zero-phase irfft via rotation recurrence (threads<128) ----
  float irv = 0.f;
  if (tid < 128) {
    const float phi = (float)tid * (1.0f / 128.0f);
    const float c1 = __builtin_amdgcn_cosf(phi);
    const float s1 = __builtin_amdgcn_sinf(phi);
    float c = 1.f, s = 0.f, accS = 0.f;
    for (int k0 = 0; k0 < 64; k0 += 4) {
      const f32x4 a4 = *(const f32x4*)&a_s[k0];
      accS = fmaf(a4[0], c, accS); ROT(c, s, c1, s1);
      accS = fmaf(a4[1], c, accS); ROT(c, s, c1, s1);
      accS = fmaf(a4[2], c, accS); ROT(c, s, c1, s1);
      accS = fmaf(a4[3], c, accS); ROT(c, s, c1, s1);
    }
    irv = (2.f * accS - a_s[0] + ((tid & 1) ? -a_s[64] : a_s[64])) * (1.0f / 128.0f);
    ir_s[tid] = irv;
  } else {
    // wave 2 (32 lanes): raw-amp sum via shuffle reduce
    const int l = tid - 128;
    float v = amp[l] + amp[l + 32] + amp[l + 64] + (l < 4 ? amp[l + 96] : 0.f);
    v += __shfl_xor(v, 16);
    v += __shfl_xor(v, 8);
    v += __shfl_xor(v, 4);
    v += __shfl_xor(v, 2);
    v += __shfl_xor(v, 1);
    if (l == 0) red_s = v;
  }
  __syncthreads();  // B2

  // ---- phase C: windowed impulse (fp16, pair-swapped), amp scaling, theta setup ----
  if (tid < 64) {
    const float w = 0.5f + 0.5f * __builtin_amdgcn_cosf((float)tid * (1.0f / 128.0f));
    imp_sw[tid ^ 1] = (_Float16)(w * irv);
  } else if (tid >= 96) {
    const int u = tid - 96;
    const float w = 0.5f - 0.5f * __builtin_amdgcn_cosf((float)u * (1.0f / 128.0f));
    imp_sw[64 + (u ^ 1)] = (_Float16)(w * ir_s[tid - 32]);
  }
  const float scale = tamp[b * T_ + t] / red_s;
  if (tid < NH_) amp[tid] *= scale;
  double th = Pv[bt] + (double)(tid + 1) * Xv[bt];
  th -= floor(th);
  const float theta = (float)th;
  const float cs = __builtin_amdgcn_cosf(theta);
  const float ss = __builtin_amdgcn_sinf(theta);
  __syncthreads();  // B3

  // ---- phase E1: harmonic additive synthesis via rotation recurrence ----
  float acc = 0.f;
  {
    float s = ss, c = cs;
    const int nv4 = (nv + 3) & ~3;
    for (int h = 0; h < nv4; h += 4) {
      const f32x4 a4 = *(const f32x4*)&amp[h];
      acc = fmaf(a4[0], s, acc); ROT(c, s, cs, ss);
      acc = fmaf(a4[1], s, acc); ROT(c, s, cs, ss);
      acc = fmaf(a4[2], s, acc); ROT(c, s, cs, ss);
      acc = fmaf(a4[3], s, acc); ROT(c, s, cs, ss);
    }
  }

  // ---- phase E2: 128-tap noise conv via packed fp16 dot2 ----
  float nf = 0.f;
  {
    const f16x2* np0;
    int pe;  // f16x2 pair index of the j=0 window
    if (tid & 1) {
      np0 = (const f16x2*)C0;
      pe = (159 + tid) >> 1;
    } else {
      np0 = (const f16x2*)C1;
      pe = (158 + tid) >> 1;
    }
    const f16x8* ip = (const f16x8*)imp_sw;
#pragma unroll
    for (int k0 = 0; k0 < 8; ++k0) {  // segment A: j = 0..63
      const f16x8 i8 = ip[k0];
      const int kb = k0 << 2;
      nf = dot2f((f16x2){i8[0], i8[1]}, np0[pe - kb], nf);
      nf = dot2f((f16x2){i8[2], i8[3]}, np0[pe - kb - 1], nf);
      nf = dot2f((f16x2){i8[4], i8[5]}, np0[pe - kb - 2], nf);
      nf = dot2f((f16x2){i8[6], i8[7]}, np0[pe - kb - 3], nf);
    }
#pragma unroll
    for (int k0 = 0; k0 < 8; ++k0) {  // segment B: j = 96..159
      const f16x8 i8 = ip[8 + k0];
      const int kb = (k0 << 2) + 48;
      nf = dot2f((f16x2){i8[0], i8[1]}, np0[pe - kb], nf);
      nf = dot2f((f16x2){i8[2], i8[3]}, np0[pe - kb - 1], nf);
      nf = dot2f((f16x2){i8[4], i8[5]}, np0[pe - kb - 2], nf);
      nf = dot2f((f16x2){i8[6], i8[7]}, np0[pe - kb - 3], nf);
    }
  }

  const float v = acc + nf;
  const unsigned k = (unsigned)(KPAD_ + t * BLK_ + tid);
  const unsigned off = ((k >> 3) << 7) + ((unsigned)b << 3) + (k & 7u);
  PH[off] = (_Float16)v;
}

// ---------------- K3: Toeplitz A-fragment table (fp16) + signal front-pad zero ----------------
// FRAG[t][lane][j] = imp[(t-14)*16 + (lane&15) - 8*(lane>>4) - j]
__global__ __launch_bounds__(512) void k_fragbuild(const float* __restrict__ rn,
                                                   const float* __restrict__ dec,
                                                   const float* __restrict__ wet,
                                                   _Float16* __restrict__ FH,
                                                   _Float16* __restrict__ PH) {
  const int t = blockIdx.x, tid = threadIdx.x;
  const int gid = t * 512 + tid;
  if (gid < 32256) ((f32x4*)PH)[gid] = (f32x4){0.f, 0.f, 0.f, 0.f};
  const int lane = tid >> 3, j = tid & 7;
  const int idx = (t - 14) * 16 + (lane & 15) - ((lane >> 4) << 3) - j;
  float v = 0.f;
  if (idx == 0) {
    v = 1.0f;
  } else if (idx > 0 && idx < REV_) {
    const float a = log1pf(expf(-dec[0]));
    const float sg = 1.f / (1.f + expf(-wet[0]));
    v = rn[idx] * expf(-a * ((float)idx / (float)SR_) * 500.0f) * sg;
  }
  FH[t * 512 + tid] = (_Float16)v;
}

// ---------------- K4: reverb as Toeplitz MFMA GEMM (single fp16 product) ----------------
static __device__ __forceinline__ f32x4 mfma_f16(f16x8 a, f16x8 b, f32x4 c) {
  return __builtin_amdgcn_mfma_f32_16x16x32_f16(a, b, c, 0, 0, 0);
}

template <int U, bool PF>
__device__ __forceinline__ void conv_step(f16x8 (&Rh)[M_], f32x4 (&acc)[M_], f16x8& bhi,
                                          const f16x8* __restrict__ ph,
                                          const f16x8* __restrict__ fh,
                                          int& kcur, int& tcur) {
  f16x8 nbh, na0, na1;
  if (PF) {
    kcur += 64;              // +32 samples = +64 f16x8 units
    nbh = ph[kcur];
    tcur -= 2;
    na0 = fh[tcur * 64];
    na1 = fh[(tcur + 1) * 64];
  }
#pragma unroll
  for (int m = 0; m < M_; ++m) {
    const int sl = (m - 2 * U) & (M_ - 1);
    acc[m] = mfma_f16(Rh[sl], bhi, acc[m]);
  }
  if (PF) {
    Rh[(M_ - 2 - 2 * U) & (M_ - 1)] = na0;
    Rh[(M_ - 1 - 2 * U) & (M_ - 1)] = na1;
    bhi = nbh;
  }
}

__global__ __launch_bounds__(512) void k_mconv(const f16x8* __restrict__ FH,
                                               const f16x8* __restrict__ PH,
                                               float* __restrict__ out) {
  const int tid = threadIdx.x;
  const int s = tid >> 6, lane = tid & 63;
  int w = blockIdx.x;
  {  // bijective XCD swizzle, nwg=500 (q=62, r=4)
    const int q = NWG_ / 8, r = NWG_ % 8;
    const int xcd = w & 7, o = w >> 3;
    w = (xcd < r ? xcd * (q + 1) : r * (q + 1) + (xcd - r) * q) + o;
  }
  const int Q0 = w << 7;                    // 128 outputs per tile
  const int T0 = 1014 - 126 * s;            // frag-table index at step 0, m=0

  const f16x8* fh = FH + lane;
  f16x8 Rh[M_];
#pragma unroll
  for (int m = 0; m < M_; ++m) Rh[m] = fh[(T0 + m) * 64];
  f32x4 acc[M_];
#pragma unroll
  for (int m = 0; m < M_; ++m) acc[m] = (f32x4){0.f, 0.f, 0.f, 0.f};

  const f16x8* ph = PH + ((lane >> 4) << 4) + (lane & 15);
  int kcur = (Q0 + 128 + 2016 * s) << 1;    // unit index of chunk base
  int tcur = T0;
  f16x8 bhi = ph[kcur];

  for (int ii = 0; ii < 15; ++ii) {         // 60 steps
    conv_step<0, true>(Rh, acc, bhi, ph, fh, kcur, tcur);
    conv_step<1, true>(Rh, acc, bhi, ph, fh, kcur, tcur);
    conv_step<2, true>(Rh, acc, bhi, ph, fh, kcur, tcur);
    conv_step<3, true>(Rh, acc, bhi, ph, fh, kcur, tcur);
  }
  conv_step<0, true>(Rh, acc, bhi, ph, fh, kcur, tcur);    // 61
  conv_step<1, true>(Rh, acc, bhi, ph, fh, kcur, tcur);    // 62
  conv_step<2, false>(Rh, acc, bhi, ph, fh, kcur, tcur);   // 63

  // two-stage cross-wave (K-split) reduction in LDS, then coalesced stores
  __shared__ f32x4 part[4][M_][64];
  if (s < 4) {
#pragma unroll
    for (int m = 0; m < M_; ++m) part[s][m][lane] = acc[m];
  }
  __syncthreads();
  if (s >= 4) {
#pragma unroll
    for (int m = 0; m < M_; ++m) part[s - 4][m][lane] += acc[m];
  }
  __syncthreads();
  {
    const int m = tid >> 6, ln = tid & 63;
    f32x4 v = part[0][m][ln];
    v += part[1][m][ln];
    v += part[2][m][ln];
    v += part[3][m][ln];
    const int b = ln & 15, g = ln >> 4;
    *(f32x4*)(out + (size_t)b * N_ + Q0 + (m << 4) + (g << 2)) = v;
  }
}

extern "C" void kernel_launch(void* const* d_in, const int* in_sizes, int n_in,
                              void* d_out, int out_size, void* d_ws, size_t ws_size,
                              hipStream_t stream) {
  const float* pitch = (const float*)d_in[0];
  const float* tamp  = (const float*)d_in[1];
  const float* harmo = (const float*)d_in[2];
  const float* nfilt = (const float*)d_in[3];
  const float* noise = (const float*)d_in[4];
  const float* rn    = (const float*)d_in[5];
  const float* dec   = (const float*)d_in[6];
  const float* wet   = (const float*)d_in[7];

  char* ws = (char*)d_ws;
  size_t off = 0;
  _Float16* PH = (_Float16*)(ws + off); off += (size_t)KTOT_ * 16 * 2;   // 2.56 MB
  _Float16* FH = (_Float16*)(ws + off); off += (size_t)NT_ * 512 * 2;    // 1.05 MB
  double* Pv = (double*)(ws + off);     off += (size_t)B_ * T_ * 8;
  double* Xv = (double*)(ws + off);     off += (size_t)B_ * T_ * 8;
  float* out = (float*)d_out;

  k_prefix<<<dim3(B_), dim3(512), 0, stream>>>(pitch, Pv, Xv);
  k_synth<<<dim3(B_ * T_), dim3(160), 0, stream>>>(pitch, tamp, harmo, nfilt, noise, Pv, Xv, PH);
  k_fragbuild<<<dim3(NT_), dim3(512), 0, stream>>>(rn, dec, wet, FH, PH);
  k_mconv<<<dim3(NWG_), dim3(512), 0, stream>>>((const f16x8*)FH, (const f16x8*)PH, out);
}

// Round 7
// 71.096 us; speedup vs baseline: 2.4759x; 1.0366x over previous
//
#include <hip/hip_runtime.h>

#define B_ 16
#define T_ 400
#define NH_ 100
#define NB_ 65
#define BLK_ 160
#define SR_ 16000
#define N_ 64000           // T_*BLK_
#define REV_ 16000
#define KPAD_ 16128        // front zero pad of signal
#define KTOT_ 80128        // KPAD_ + N_
#define NT_ 1022           // Toeplitz frag table entries, t in [0,1021]
#define KSPLIT_ 8
#define STEPS_ 63          // 504 chunks / KSPLIT_
#define M_ 8               // m-tiles per wave (128 outputs)
#define NWG_ 500

typedef __attribute__((ext_vector_type(8))) _Float16 f16x8;
typedef __attribute__((ext_vector_type(2))) _Float16 f16x2;
typedef __attribute__((ext_vector_type(4))) float f32x4;

// complex rotation: (c,s) *= (c1,s1)
#define ROT(c, s, c1, s1)                                   \
  {                                                         \
    float _t = (c) * (s1);                                  \
    float _u = (s) * (s1);                                  \
    float _ns = fmaf((s), (c1), _t);                        \
    (c) = fmaf((c), (c1), -_u);                             \
    (s) = _ns;                                              \
  }

static __device__ __forceinline__ float dot2f(f16x2 a, f16x2 b, float c) {
#if __has_builtin(__builtin_amdgcn_fdot2)
  return __builtin_amdgcn_fdot2(a, b, c, false);
#else
  return fmaf((float)a[0], (float)b[0], fmaf((float)a[1], (float)b[1], c));
#endif
}

// ---------------- K0: merged fp64 prefix (16 blocks) + Toeplitz frag table (1022 blocks) ----------------
// FRAG[t][lane][j] = imp[(t-14)*16 + (lane&15) - 8*(lane>>4) - j]
__global__ __launch_bounds__(512) void k_pre(const float* __restrict__ pitch,
                                             const float* __restrict__ rn,
                                             const float* __restrict__ dec,
                                             const float* __restrict__ wet,
                                             double* __restrict__ Pv,
                                             double* __restrict__ Xv,
                                             _Float16* __restrict__ FH,
                                             _Float16* __restrict__ PH) {
  const int blk = blockIdx.x, tid = threadIdx.x;
  if (blk >= NT_) {
    // ---- prefix branch ----
    __shared__ double s[512];
    const int b = blk - NT_, t = tid;
    double x = 0.0;
    if (t < T_) x = (double)pitch[b * T_ + t] * (1.0 / (double)SR_);
    s[t] = x;
    __syncthreads();
    for (int off = 1; off < 512; off <<= 1) {
      double v = (t >= off) ? s[t - off] : 0.0;
      __syncthreads();
      s[t] += v;
      __syncthreads();
    }
    if (t < T_) {
      Xv[b * T_ + t] = x;
      Pv[b * T_ + t] = (s[t] - x) * 160.0;
    }
    return;
  }
  // ---- fragbuild branch ----
  const int t = blk;
  const int gid = t * 512 + tid;
  if (gid < 32256) ((f32x4*)PH)[gid] = (f32x4){0.f, 0.f, 0.f, 0.f};
  const int lane = tid >> 3, j = tid & 7;
  const int idx = (t - 14) * 16 + (lane & 15) - ((lane >> 4) << 3) - j;
  float v = 0.f;
  if (idx == 0) {
    v = 1.0f;
  } else if (idx > 0 && idx < REV_) {
    const float a = log1pf(expf(-dec[0]));
    const float sg = 1.f / (1.f + expf(-wet[0]));
    v = rn[idx] * expf(-a * ((float)idx / (float)SR_) * 500.0f) * sg;
  }
  FH[t * 512 + tid] = (_Float16)v;
}

// ---------------- K2: per-(b,t) harmonic synth + filtered noise -> packed fp16 ----------------
__global__ __launch_bounds__(160) void k_synth(
    const float* __restrict__ pitch, const float* __restrict__ tamp,
    const float* __restrict__ harmo, const float* __restrict__ nfilt,
    const float* __restrict__ noise, const double* __restrict__ Pv,
    const double* __restrict__ Xv, _Float16* __restrict__ PH) {
  const int bt = blockIdx.x, b = bt / T_, t = bt - b * T_;
  const int tid = threadIdx.x;
  __shared__ __align__(16) float amp[104];
  __shared__ __align__(16) float a_s[NB_ + 3];
  __shared__ __align__(16) float ir_s[68];
  __shared__ __align__(16) _Float16 C0[320];      // noi_pad (160 zeros + noise)
  __shared__ __align__(16) _Float16 C1[320];      // shifted copy: C1[x] = noi_pad[x+1]
  __shared__ __align__(16) _Float16 imp_sw[128];  // [0..63] segA, [64..127] segB, pair-swapped
  __shared__ float red_s;

  const float pv = pitch[b * T_ + t];
  // n_valid: largest h (1-based) with fp32(h*pv) < 8000, capped at 100
  int nv = (int)(8000.0f / pv);
  if (nv > NH_) nv = NH_;
  while (nv < NH_ && (float)(nv + 1) * pv < 8000.0f) ++nv;
  while (nv > 0 && (float)nv * pv >= 8000.0f) --nv;

  // ---- phase A: loads/staging ----
  if (tid < NB_) a_s[tid] = nfilt[bt * NB_ + tid];
  {
    const _Float16 nh = (_Float16)noise[bt * BLK_ + tid];
    C0[160 + tid] = nh;
    C1[159 + tid] = nh;
    C0[tid] = (_Float16)0.f;
    if (tid < 159) C1[tid] = (_Float16)0.f;
  }
  if (tid < NH_) {
    const float ha = harmo[(b * NH_ + tid) * T_ + t];
    const float aa = (pv * (float)(tid + 1) < 8000.0f ? 1.0f : 0.0f) + 1e-4f;
    amp[tid] = ha * aa;
  } else if (tid < 104) {
    amp[tid] = 0.f;
  }
  __syncthreads();  // B1

  // ---- phase B: 128-pt zero-phase irfft, symmetric half (i<=64), 4-strand rotation ----
  float irv = 0.f;
  if (tid < 65) {
    const float phi = (float)tid * (1.0f / 128.0f);
    const float c1 = __builtin_amdgcn_cosf(phi);
    const float s1 = __builtin_amdgcn_sinf(phi);
    // strand bases: angles 0,1,2,3 * phi; step rotator = 4*phi
    float c2 = fmaf(c1, c1, -s1 * s1), s2 = 2.f * c1 * s1;
    float c3 = fmaf(c2, c1, -s2 * s1), s3 = fmaf(s2, c1, c2 * s1);
    const float c4 = fmaf(c2, c2, -s2 * s2), s4 = 2.f * c2 * s2;
    float r0c = 1.f, r0s = 0.f;
    float r1c = c1, r1s = s1;
    float r2c = c2, r2s = s2;
    float r3c = c3, r3s = s3;
    float a0 = 0.f, a1 = 0.f, a2 = 0.f, a3 = 0.f;
#pragma unroll
    for (int m = 0; m < 16; ++m) {
      const f32x4 a4 = *(const f32x4*)&a_s[m << 2];
      a0 = fmaf(a4[0], r0c, a0); ROT(r0c, r0s, c4, s4);
      a1 = fmaf(a4[1], r1c, a1); ROT(r1c, r1s, c4, s4);
      a2 = fmaf(a4[2], r2c, a2); ROT(r2c, r2s, c4, s4);
      a3 = fmaf(a4[3], r3c, a3); ROT(r3c, r3s, c4, s4);
    }
    const float accS = (a0 + a1) + (a2 + a3);
    irv = (2.f * accS - a_s[0] + ((tid & 1) ? -a_s[64] : a_s[64])) * (1.0f / 128.0f);
    ir_s[tid] = irv;
  } else if (tid >= 128) {
    // wave 2 (32 lanes): raw-amp sum via shuffle reduce
    const int l = tid - 128;
    float v = amp[l] + amp[l + 32] + amp[l + 64] + (l < 4 ? amp[l + 96] : 0.f);
    v += __shfl_xor(v, 16);
    v += __shfl_xor(v, 8);
    v += __shfl_xor(v, 4);
    v += __shfl_xor(v, 2);
    v += __shfl_xor(v, 1);
    if (l == 0) red_s = v;
  }
  __syncthreads();  // B2

  // ---- phase C: windowed impulse (fp16, pair-swapped; uses ir symmetry), theta setup ----
  if (tid < 64) {
    const float w = 0.5f + 0.5f * __builtin_amdgcn_cosf((float)tid * (1.0f / 128.0f));
    imp_sw[tid ^ 1] = (_Float16)(w * irv);
  } else if (tid >= 96) {
    const int u = tid - 96;
    const float w = 0.5f - 0.5f * __builtin_amdgcn_cosf((float)u * (1.0f / 128.0f));
    imp_sw[64 + (u ^ 1)] = (_Float16)(w * ir_s[64 - u]);
  }
  const float scale = tamp[b * T_ + t] / red_s;
  double th = Pv[bt] + (double)(tid + 1) * Xv[bt];
  th -= floor(th);
  const float theta = (float)th;
  const float cT = __builtin_amdgcn_cosf(theta);
  const float sT = __builtin_amdgcn_sinf(theta);
  __syncthreads();  // B3

  // ---- phase E1: harmonic additive synthesis, 4-strand rotation ----
  float acc;
  {
    // strand bases: angles 1,2,3,4 * theta; step rotator = 4*theta
    float c2 = fmaf(cT, cT, -sT * sT), s2 = 2.f * cT * sT;
    float c3 = fmaf(c2, cT, -s2 * sT), s3 = fmaf(s2, cT, c2 * sT);
    const float c4 = fmaf(c2, c2, -s2 * s2), s4 = 2.f * c2 * s2;
    float rAc = cT, rAs = sT;
    float rBc = c2, rBs = s2;
    float rCc = c3, rCs = s3;
    float rDc = c4, rDs = s4;
    float a0 = 0.f, a1 = 0.f, a2 = 0.f, a3 = 0.f;
    const int S = (nv + 3) >> 2;
    for (int m = 0; m < S; ++m) {
      const f32x4 a4 = *(const f32x4*)&amp[m << 2];
      a0 = fmaf(a4[0], rAs, a0); ROT(rAc, rAs, c4, s4);
      a1 = fmaf(a4[1], rBs, a1); ROT(rBc, rBs, c4, s4);
      a2 = fmaf(a4[2], rCs, a2); ROT(rCc, rCs, c4, s4);
      a3 = fmaf(a4[3], rDs, a3); ROT(rDc, rDs, c4, s4);
    }
    acc = ((a0 + a1) + (a2 + a3)) * scale;
  }

  // ---- phase E2: 128-tap noise conv via packed fp16 dot2 ----
  float nf = 0.f;
  {
    const f16x2* np0;
    int pe;  // f16x2 pair index of the j=0 window
    if (tid & 1) {
      np0 = (const f16x2*)C0;
      pe = (159 + tid) >> 1;
    } else {
      np0 = (const f16x2*)C1;
      pe = (158 + tid) >> 1;
    }
    const f16x8* ip = (const f16x8*)imp_sw;
#pragma unroll
    for (int k0 = 0; k0 < 8; ++k0) {  // segment A: j = 0..63
      const f16x8 i8 = ip[k0];
      const int kb = k0 << 2;
      nf = dot2f((f16x2){i8[0], i8[1]}, np0[pe - kb], nf);
      nf = dot2f((f16x2){i8[2], i8[3]}, np0[pe - kb - 1], nf);
      nf = dot2f((f16x2){i8[4], i8[5]}, np0[pe - kb - 2], nf);
      nf = dot2f((f16x2){i8[6], i8[7]}, np0[pe - kb - 3], nf);
    }
#pragma unroll
    for (int k0 = 0; k0 < 8; ++k0) {  // segment B: j = 96..159
      const f16x8 i8 = ip[8 + k0];
      const int kb = (k0 << 2) + 48;
      nf = dot2f((f16x2){i8[0], i8[1]}, np0[pe - kb], nf);
      nf = dot2f((f16x2){i8[2], i8[3]}, np0[pe - kb - 1], nf);
      nf = dot2f((f16x2){i8[4], i8[5]}, np0[pe - kb - 2], nf);
      nf = dot2f((f16x2){i8[6], i8[7]}, np0[pe - kb - 3], nf);
    }
  }

  const float v = acc + nf;
  const unsigned k = (unsigned)(KPAD_ + t * BLK_ + tid);
  const unsigned off = ((k >> 3) << 7) + ((unsigned)b << 3) + (k & 7u);
  PH[off] = (_Float16)v;
}

// ---------------- K4: reverb as Toeplitz MFMA GEMM (single fp16 product) ----------------
static __device__ __forceinline__ f32x4 mfma_f16(f16x8 a, f16x8 b, f32x4 c) {
  return __builtin_amdgcn_mfma_f32_16x16x32_f16(a, b, c, 0, 0, 0);
}

template <int U, bool PF>
__device__ __forceinline__ void conv_step(f16x8 (&Rh)[M_], f32x4 (&acc)[M_], f16x8& bhi,
                                          const f16x8* __restrict__ ph,
                                          const f16x8* __restrict__ fh,
                                          int& kcur, int& tcur) {
  f16x8 nbh, na0, na1;
  if (PF) {
    kcur += 64;              // +32 samples = +64 f16x8 units
    nbh = ph[kcur];
    tcur -= 2;
    na0 = fh[tcur * 64];
    na1 = fh[(tcur + 1) * 64];
  }
#pragma unroll
  for (int m = 0; m < M_; ++m) {
    const int sl = (m - 2 * U) & (M_ - 1);
    acc[m] = mfma_f16(Rh[sl], bhi, acc[m]);
  }
  if (PF) {
    Rh[(M_ - 2 - 2 * U) & (M_ - 1)] = na0;
    Rh[(M_ - 1 - 2 * U) & (M_ - 1)] = na1;
    bhi = nbh;
  }
}

__global__ __launch_bounds__(512) void k_mconv(const f16x8* __restrict__ FH,
                                               const f16x8* __restrict__ PH,
                                               float* __restrict__ out) {
  const int tid = threadIdx.x;
  const int s = tid >> 6, lane = tid & 63;
  int w = blockIdx.x;
  {  // bijective XCD swizzle, nwg=500 (q=62, r=4)
    const int q = NWG_ / 8, r = NWG_ % 8;
    const int xcd = w & 7, o = w >> 3;
    w = (xcd < r ? xcd * (q + 1) : r * (q + 1) + (xcd - r) * q) + o;
  }
  const int Q0 = w << 7;                    // 128 outputs per tile
  const int T0 = 1014 - 126 * s;            // frag-table index at step 0, m=0

  const f16x8* fh = FH + lane;
  f16x8 Rh[M_];
#pragma unroll
  for (int m = 0; m < M_; ++m) Rh[m] = fh[(T0 + m) * 64];
  f32x4 acc[M_];
#pragma unroll
  for (int m = 0; m < M_; ++m) acc[m] = (f32x4){0.f, 0.f, 0.f, 0.f};

  const f16x8* ph = PH + ((lane >> 4) << 4) + (lane & 15);
  int kcur = (Q0 + 128 + 2016 * s) << 1;    // unit index of chunk base
  int tcur = T0;
  f16x8 bhi = ph[kcur];

  for (int ii = 0; ii < 15; ++ii) {         // 60 steps
    conv_step<0, true>(Rh, acc, bhi, ph, fh, kcur, tcur);
    conv_step<1, true>(Rh, acc, bhi, ph, fh, kcur, tcur);
    conv_step<2, true>(Rh, acc, bhi, ph, fh, kcur, tcur);
    conv_step<3, true>(Rh, acc, bhi, ph, fh, kcur, tcur);
  }
  conv_step<0, true>(Rh, acc, bhi, ph, fh, kcur, tcur);    // 61
  conv_step<1, true>(Rh, acc, bhi, ph, fh, kcur, tcur);    // 62
  conv_step<2, false>(Rh, acc, bhi, ph, fh, kcur, tcur);   // 63

  // two-stage cross-wave (K-split) reduction in LDS, then coalesced stores
  __shared__ f32x4 part[4][M_][64];
  if (s < 4) {
#pragma unroll
    for (int m = 0; m < M_; ++m) part[s][m][lane] = acc[m];
  }
  __syncthreads();
  if (s >= 4) {
#pragma unroll
    for (int m = 0; m < M_; ++m) part[s - 4][m][lane] += acc[m];
  }
  __syncthreads();
  {
    const int m = tid >> 6, ln = tid & 63;
    f32x4 v = part[0][m][ln];
    v += part[1][m][ln];
    v += part[2][m][ln];
    v += part[3][m][ln];
    const int b = ln & 15, g = ln >> 4;
    *(f32x4*)(out + (size_t)b * N_ + Q0 + (m << 4) + (g << 2)) = v;
  }
}

extern "C" void kernel_launch(void* const* d_in, const int* in_sizes, int n_in,
                              void* d_out, int out_size, void* d_ws, size_t ws_size,
                              hipStream_t stream) {
  const float* pitch = (const float*)d_in[0];
  const float* tamp  = (const float*)d_in[1];
  const float* harmo = (const float*)d_in[2];
  const float* nfilt = (const float*)d_in[3];
  const float* noise = (const float*)d_in[4];
  const float* rn    = (const float*)d_in[5];
  const float* dec   = (const float*)d_in[6];
  const float* wet   = (const float*)d_in[7];

  char* ws = (char*)d_ws;
  size_t off = 0;
  _Float16* PH = (_Float16*)(ws + off); off += (size_t)KTOT_ * 16 * 2;   // 2.56 MB
  _Float16* FH = (_Float16*)(ws + off); off += (size_t)NT_ * 512 * 2;    // 1.05 MB
  double* Pv = (double*)(ws + off);     off += (size_t)B_ * T_ * 8;
  double* Xv = (double*)(ws + off);     off += (size_t)B_ * T_ * 8;
  float* out = (float*)d_out;

  k_pre<<<dim3(NT_ + B_), dim3(512), 0, stream>>>(pitch, rn, dec, wet, Pv, Xv, FH, PH);
  k_synth<<<dim3(B_ * T_), dim3(160), 0, stream>>>(pitch, tamp, harmo, nfilt, noise, Pv, Xv, PH);
  k_mconv<<<dim3(NWG_), dim3(512), 0, stream>>>((const f16x8*)FH, (const f16x8*)PH, out);
}

// Round 8
// 68.275 us; speedup vs baseline: 2.5782x; 1.0413x over previous
//
#include <hip/hip_runtime.h>

#define B_ 16
#define T_ 400
#define NH_ 100
#define NB_ 65
#define BLK_ 160
#define SR_ 16000
#define N_ 64000           // T_*BLK_
#define REV_ 16000
#define KPAD_ 16128        // front zero pad of signal
#define KTOT_ 80128        // KPAD_ + N_
#define NT_ 1022           // Toeplitz frag table entries, t in [0,1021]
#define KSPLIT_ 8
#define STEPS_ 63          // 504 chunks / KSPLIT_
#define M_ 8               // m-tiles per wave (128 outputs)
#define NWG_ 500

typedef __attribute__((ext_vector_type(8))) _Float16 f16x8;
typedef __attribute__((ext_vector_type(2))) _Float16 f16x2;
typedef __attribute__((ext_vector_type(4))) float f32x4;

static __device__ __forceinline__ float dot2f(f16x2 a, f16x2 b, float c) {
#if __has_builtin(__builtin_amdgcn_fdot2)
  return __builtin_amdgcn_fdot2(a, b, c, false);
#else
  return fmaf((float)a[0], (float)b[0], fmaf((float)a[1], (float)b[1], c));
#endif
}

// ---------------- K0: merged fp64 prefix (16 blocks) + Toeplitz frag table (1022 blocks) ----------------
// FRAG[t][lane][j] = imp[(t-14)*16 + (lane&15) - 8*(lane>>4) - j]
__global__ __launch_bounds__(512) void k_pre(const float* __restrict__ pitch,
                                             const float* __restrict__ rn,
                                             const float* __restrict__ dec,
                                             const float* __restrict__ wet,
                                             double* __restrict__ Pv,
                                             double* __restrict__ Xv,
                                             _Float16* __restrict__ FH,
                                             _Float16* __restrict__ PH) {
  const int blk = blockIdx.x, tid = threadIdx.x;
  if (blk >= NT_) {
    // ---- prefix branch ----
    __shared__ double s[512];
    const int b = blk - NT_, t = tid;
    double x = 0.0;
    if (t < T_) x = (double)pitch[b * T_ + t] * (1.0 / (double)SR_);
    s[t] = x;
    __syncthreads();
    for (int off = 1; off < 512; off <<= 1) {
      double v = (t >= off) ? s[t - off] : 0.0;
      __syncthreads();
      s[t] += v;
      __syncthreads();
    }
    if (t < T_) {
      Xv[b * T_ + t] = x;
      Pv[b * T_ + t] = (s[t] - x) * 160.0;
    }
    return;
  }
  // ---- fragbuild branch ----
  const int t = blk;
  const int gid = t * 512 + tid;
  if (gid < 32256) ((f32x4*)PH)[gid] = (f32x4){0.f, 0.f, 0.f, 0.f};
  const int lane = tid >> 3, j = tid & 7;
  const int idx = (t - 14) * 16 + (lane & 15) - ((lane >> 4) << 3) - j;
  float v = 0.f;
  if (idx == 0) {
    v = 1.0f;
  } else if (idx > 0 && idx < REV_) {
    const float a = log1pf(expf(-dec[0]));
    const float sg = 1.f / (1.f + expf(-wet[0]));
    v = rn[idx] * expf(-a * ((float)idx / (float)SR_) * 500.0f) * sg;
  }
  FH[t * 512 + tid] = (_Float16)v;
}

// ---------------- K2: dual-column harmonic synth + filtered noise -> packed fp16 ----------------
// 320 threads = 5 full waves; group g in {0,1} handles bt = 2*blk+g with local tid ltid in [0,160).
__global__ __launch_bounds__(320) void k_synth(
    const float* __restrict__ pitch, const float* __restrict__ tamp,
    const float* __restrict__ harmo, const float* __restrict__ nfilt,
    const float* __restrict__ noise, const double* __restrict__ Pv,
    const double* __restrict__ Xv, _Float16* __restrict__ PH) {
  const int tid = threadIdx.x;
  const int g = (tid >= 160) ? 1 : 0;
  const int ltid = tid - (g << 7) - (g << 5);  // tid - 160*g
  const int bt = (blockIdx.x << 1) + g;
  const int b = bt / T_, t = bt - b * T_;
  __shared__ __align__(16) float amp[2][112];
  __shared__ __align__(16) float a_s[2][68];
  __shared__ __align__(16) float ir_s[2][68];
  __shared__ __align__(16) _Float16 C0[2][320];      // noi_pad (160 zeros + noise)
  __shared__ __align__(16) _Float16 C1[2][320];      // shifted copy: C1[x] = noi_pad[x+1]
  __shared__ __align__(16) _Float16 imp_sw[2][128];  // [0..63] segA, [64..127] segB, pair-swapped
  __shared__ float red_s[2];

  const float pv = pitch[bt];
  // n_valid: largest h (1-based) with fp32(h*pv) < 8000, capped at 100
  int nv = (int)(8000.0f / pv);
  if (nv > NH_) nv = NH_;
  while (nv < NH_ && (float)(nv + 1) * pv < 8000.0f) ++nv;
  while (nv > 0 && (float)nv * pv >= 8000.0f) --nv;

  // ---- phase A: loads/staging ----
  if (ltid < NB_) a_s[g][ltid] = nfilt[bt * NB_ + ltid];
  {
    const _Float16 nh = (_Float16)noise[bt * BLK_ + ltid];
    C0[g][160 + ltid] = nh;
    C1[g][159 + ltid] = nh;
    C0[g][ltid] = (_Float16)0.f;
    if (ltid < 159) C1[g][ltid] = (_Float16)0.f;
  }
  if (ltid < NH_) {
    const float ha = harmo[(b * NH_ + ltid) * T_ + t];
    const float aa = (pv * (float)(ltid + 1) < 8000.0f ? 1.0f : 0.0f) + 1e-4f;
    amp[g][ltid] = ha * aa;
  } else if (ltid < 112) {
    amp[g][ltid] = 0.f;
  }
  __syncthreads();  // B1

  // ---- phase B: 128-pt zero-phase irfft, symmetric half (i<=64), Chebyshev 4-strand ----
  float irv = 0.f;
  if (ltid < 65) {
    const float phi = (float)ltid * (1.0f / 128.0f);
    const float c1 = __builtin_amdgcn_cosf(phi);
    const float c2 = fmaf(2.f * c1, c1, -1.f);
    const float c3 = fmaf(2.f * c2, c1, -c1);
    const float c4 = fmaf(2.f * c2, c2, -1.f);
    const float tc = 2.f * c4;
    float x0 = 1.f, p0 = c4;
    float x1 = c1, p1 = c3;
    float x2 = c2, p2 = c2;
    float x3 = c3, p3 = c1;
    float a0 = 0.f, a1 = 0.f, a2 = 0.f, a3 = 0.f;
#pragma unroll
    for (int m = 0; m < 8; ++m) {
      const f32x4 aA = *(const f32x4*)&a_s[g][m << 3];
      const f32x4 aB = *(const f32x4*)&a_s[g][(m << 3) + 4];
      a0 = fmaf(aA[0], x0, a0); const float y0 = fmaf(tc, x0, -p0);
      a1 = fmaf(aA[1], x1, a1); const float y1 = fmaf(tc, x1, -p1);
      a2 = fmaf(aA[2], x2, a2); const float y2 = fmaf(tc, x2, -p2);
      a3 = fmaf(aA[3], x3, a3); const float y3 = fmaf(tc, x3, -p3);
      a0 = fmaf(aB[0], y0, a0); const float z0 = fmaf(tc, y0, -x0); p0 = y0; x0 = z0;
      a1 = fmaf(aB[1], y1, a1); const float z1 = fmaf(tc, y1, -x1); p1 = y1; x1 = z1;
      a2 = fmaf(aB[2], y2, a2); const float z2 = fmaf(tc, y2, -x2); p2 = y2; x2 = z2;
      a3 = fmaf(aB[3], y3, a3); const float z3 = fmaf(tc, y3, -x3); p3 = y3; x3 = z3;
    }
    const float accS = (a0 + a1) + (a2 + a3);
    irv = (2.f * accS - a_s[g][0] + ((ltid & 1) ? -a_s[g][64] : a_s[g][64])) * (1.0f / 128.0f);
    ir_s[g][ltid] = irv;
  } else if (ltid >= 128) {
    // 32 lanes: raw-amp sum via shuffle reduce (xor<=16 stays within 32-lane half)
    const int l = ltid - 128;
    float v = amp[g][l] + amp[g][l + 32] + amp[g][l + 64] + (l < 4 ? amp[g][l + 96] : 0.f);
    v += __shfl_xor(v, 16);
    v += __shfl_xor(v, 8);
    v += __shfl_xor(v, 4);
    v += __shfl_xor(v, 2);
    v += __shfl_xor(v, 1);
    if (l == 0) red_s[g] = v;
  }
  __syncthreads();  // B2

  // ---- phase C: windowed impulse (fp16, pair-swapped; uses ir symmetry), theta setup ----
  if (ltid < 64) {
    const float w = 0.5f + 0.5f * __builtin_amdgcn_cosf((float)ltid * (1.0f / 128.0f));
    imp_sw[g][ltid ^ 1] = (_Float16)(w * irv);
  } else if (ltid >= 96 && ltid < 160) {
    const int u = ltid - 96;
    const float w = 0.5f - 0.5f * __builtin_amdgcn_cosf((float)u * (1.0f / 128.0f));
    imp_sw[g][64 + (u ^ 1)] = (_Float16)(w * ir_s[g][64 - u]);
  }
  const float scale = tamp[bt] / red_s[g];
  double th = Pv[bt] + (double)(ltid + 1) * Xv[bt];
  th -= floor(th);
  const float theta = (float)th;
  const float cT = __builtin_amdgcn_cosf(theta);
  const float sT = __builtin_amdgcn_sinf(theta);
  __syncthreads();  // B3

  // ---- phase E1: harmonic additive synthesis, Chebyshev 4-strand ----
  float acc;
  {
    const float c2 = fmaf(cT, cT, -sT * sT);
    const float s2 = 2.f * cT * sT;
    const float s3 = fmaf(s2, cT, c2 * sT);
    const float s4 = 2.f * s2 * c2;
    const float c4 = fmaf(2.f * c2, c2, -1.f);
    const float tc = 2.f * c4;
    float x0 = sT, p0 = -s3;
    float x1 = s2, p1 = -s2;
    float x2 = s3, p2 = -sT;
    float x3 = s4, p3 = 0.f;
    float a0 = 0.f, a1 = 0.f, a2 = 0.f, a3 = 0.f;
    const int S = (nv + 7) >> 3;
    for (int m = 0; m < S; ++m) {
      const f32x4 aA = *(const f32x4*)&amp[g][m << 3];
      const f32x4 aB = *(const f32x4*)&amp[g][(m << 3) + 4];
      a0 = fmaf(aA[0], x0, a0); const float y0 = fmaf(tc, x0, -p0);
      a1 = fmaf(aA[1], x1, a1); const float y1 = fmaf(tc, x1, -p1);
      a2 = fmaf(aA[2], x2, a2); const float y2 = fmaf(tc, x2, -p2);
      a3 = fmaf(aA[3], x3, a3); const float y3 = fmaf(tc, x3, -p3);
      a0 = fmaf(aB[0], y0, a0); const float z0 = fmaf(tc, y0, -x0); p0 = y0; x0 = z0;
      a1 = fmaf(aB[1], y1, a1); const float z1 = fmaf(tc, y1, -x1); p1 = y1; x1 = z1;
      a2 = fmaf(aB[2], y2, a2); const float z2 = fmaf(tc, y2, -x2); p2 = y2; x2 = z2;
      a3 = fmaf(aB[3], y3, a3); const float z3 = fmaf(tc, y3, -x3); p3 = y3; x3 = z3;
    }
    acc = ((a0 + a1) + (a2 + a3)) * scale;
  }

  // ---- phase E2: 128-tap noise conv via packed fp16 dot2 ----
  float nf = 0.f;
  {
    const f16x2* np0;
    int pe;  // f16x2 pair index of the j=0 window
    if (ltid & 1) {
      np0 = (const f16x2*)C0[g];
      pe = (159 + ltid) >> 1;
    } else {
      np0 = (const f16x2*)C1[g];
      pe = (158 + ltid) >> 1;
    }
    const f16x8* ip = (const f16x8*)imp_sw[g];
#pragma unroll
    for (int k0 = 0; k0 < 8; ++k0) {  // segment A: j = 0..63
      const f16x8 i8 = ip[k0];
      const int kb = k0 << 2;
      nf = dot2f((f16x2){i8[0], i8[1]}, np0[pe - kb], nf);
      nf = dot2f((f16x2){i8[2], i8[3]}, np0[pe - kb - 1], nf);
      nf = dot2f((f16x2){i8[4], i8[5]}, np0[pe - kb - 2], nf);
      nf = dot2f((f16x2){i8[6], i8[7]}, np0[pe - kb - 3], nf);
    }
#pragma unroll
    for (int k0 = 0; k0 < 8; ++k0) {  // segment B: j = 96..159
      const f16x8 i8 = ip[8 + k0];
      const int kb = (k0 << 2) + 48;
      nf = dot2f((f16x2){i8[0], i8[1]}, np0[pe - kb], nf);
      nf = dot2f((f16x2){i8[2], i8[3]}, np0[pe - kb - 1], nf);
      nf = dot2f((f16x2){i8[4], i8[5]}, np0[pe - kb - 2], nf);
      nf = dot2f((f16x2){i8[6], i8[7]}, np0[pe - kb - 3], nf);
    }
  }

  const float v = acc + nf;
  const unsigned k = (unsigned)(KPAD_ + t * BLK_ + ltid);
  const unsigned off = ((k >> 3) << 7) + ((unsigned)b << 3) + (k & 7u);
  PH[off] = (_Float16)v;
}

// ---------------- K4: reverb as Toeplitz MFMA GEMM (single fp16 product) ----------------
static __device__ __forceinline__ f32x4 mfma_f16(f16x8 a, f16x8 b, f32x4 c) {
  return __builtin_amdgcn_mfma_f32_16x16x32_f16(a, b, c, 0, 0, 0);
}

template <int U, bool PF>
__device__ __forceinline__ void conv_step(f16x8 (&Rh)[M_], f32x4 (&acc)[M_], f16x8& bhi,
                                          const f16x8* __restrict__ ph,
                                          const f16x8* __restrict__ fh,
                                          int& kcur, int& tcur) {
  f16x8 nbh, na0, na1;
  if (PF) {
    kcur += 64;              // +32 samples = +64 f16x8 units
    nbh = ph[kcur];
    tcur -= 2;
    na0 = fh[tcur * 64];
    na1 = fh[(tcur + 1) * 64];
  }
#pragma unroll
  for (int m = 0; m < M_; ++m) {
    const int sl = (m - 2 * U) & (M_ - 1);
    acc[m] = mfma_f16(Rh[sl], bhi, acc[m]);
  }
  if (PF) {
    Rh[(M_ - 2 - 2 * U) & (M_ - 1)] = na0;
    Rh[(M_ - 1 - 2 * U) & (M_ - 1)] = na1;
    bhi = nbh;
  }
}

__global__ __launch_bounds__(512) void k_mconv(const f16x8* __restrict__ FH,
                                               const f16x8* __restrict__ PH,
                                               float* __restrict__ out) {
  const int tid = threadIdx.x;
  const int s = tid >> 6, lane = tid & 63;
  int w = blockIdx.x;
  {  // bijective XCD swizzle, nwg=500 (q=62, r=4)
    const int q = NWG_ / 8, r = NWG_ % 8;
    const int xcd = w & 7, o = w >> 3;
    w = (xcd < r ? xcd * (q + 1) : r * (q + 1) + (xcd - r) * q) + o;
  }
  const int Q0 = w << 7;                    // 128 outputs per tile
  const int T0 = 1014 - 126 * s;            // frag-table index at step 0, m=0

  const f16x8* fh = FH + lane;
  f16x8 Rh[M_];
#pragma unroll
  for (int m = 0; m < M_; ++m) Rh[m] = fh[(T0 + m) * 64];
  f32x4 acc[M_];
#pragma unroll
  for (int m = 0; m < M_; ++m) acc[m] = (f32x4){0.f, 0.f, 0.f, 0.f};

  const f16x8* ph = PH + ((lane >> 4) << 4) + (lane & 15);
  int kcur = (Q0 + 128 + 2016 * s) << 1;    // unit index of chunk base
  int tcur = T0;
  f16x8 bhi = ph[kcur];

  for (int ii = 0; ii < 15; ++ii) {         // 60 steps
    conv_step<0, true>(Rh, acc, bhi, ph, fh, kcur, tcur);
    conv_step<1, true>(Rh, acc, bhi, ph, fh, kcur, tcur);
    conv_step<2, true>(Rh, acc, bhi, ph, fh, kcur, tcur);
    conv_step<3, true>(Rh, acc, bhi, ph, fh, kcur, tcur);
  }
  conv_step<0, true>(Rh, acc, bhi, ph, fh, kcur, tcur);    // 61
  conv_step<1, true>(Rh, acc, bhi, ph, fh, kcur, tcur);    // 62
  conv_step<2, false>(Rh, acc, bhi, ph, fh, kcur, tcur);   // 63

  // two-stage cross-wave (K-split) reduction in LDS, then coalesced stores
  __shared__ f32x4 part[4][M_][64];
  if (s < 4) {
#pragma unroll
    for (int m = 0; m < M_; ++m) part[s][m][lane] = acc[m];
  }
  __syncthreads();
  if (s >= 4) {
#pragma unroll
    for (int m = 0; m < M_; ++m) part[s - 4][m][lane] += acc[m];
  }
  __syncthreads();
  {
    const int m = tid >> 6, ln = tid & 63;
    f32x4 v = part[0][m][ln];
    v += part[1][m][ln];
    v += part[2][m][ln];
    v += part[3][m][ln];
    const int b = ln & 15, g = ln >> 4;
    *(f32x4*)(out + (size_t)b * N_ + Q0 + (m << 4) + (g << 2)) = v;
  }
}

extern "C" void kernel_launch(void* const* d_in, const int* in_sizes, int n_in,
                              void* d_out, int out_size, void* d_ws, size_t ws_size,
                              hipStream_t stream) {
  const float* pitch = (const float*)d_in[0];
  const float* tamp  = (const float*)d_in[1];
  const float* harmo = (const float*)d_in[2];
  const float* nfilt = (const float*)d_in[3];
  const float* noise = (const float*)d_in[4];
  const float* rn    = (const float*)d_in[5];
  const float* dec   = (const float*)d_in[6];
  const float* wet   = (const float*)d_in[7];

  char* ws = (char*)d_ws;
  size_t off = 0;
  _Float16* PH = (_Float16*)(ws + off); off += (size_t)KTOT_ * 16 * 2;   // 2.56 MB
  _Float16* FH = (_Float16*)(ws + off); off += (size_t)NT_ * 512 * 2;    // 1.05 MB
  double* Pv = (double*)(ws + off);     off += (size_t)B_ * T_ * 8;
  double* Xv = (double*)(ws + off);     off += (size_t)B_ * T_ * 8;
  float* out = (float*)d_out;

  k_pre<<<dim3(NT_ + B_), dim3(512), 0, stream>>>(pitch, rn, dec, wet, Pv, Xv, FH, PH);
  k_synth<<<dim3(B_ * T_ / 2), dim3(320), 0, stream>>>(pitch, tamp, harmo, nfilt, noise, Pv, Xv, PH);
  k_mconv<<<dim3(NWG_), dim3(512), 0, stream>>>((const f16x8*)FH, (const f16x8*)PH, out);
}

// Round 9
// 68.255 us; speedup vs baseline: 2.5790x; 1.0003x over previous
//
#include <hip/hip_runtime.h>

#define B_ 16
#define T_ 400
#define NH_ 100
#define NB_ 65
#define BLK_ 160
#define SR_ 16000
#define N_ 64000           // T_*BLK_
#define REV_ 16000
#define KPAD_ 16128        // front zero pad of signal
#define KTOT_ 80128        // KPAD_ + N_
#define NT_ 1038           // Toeplitz frag table entries, t in [0,1038)
#define M_ 8               // m-tiles per wave (128 outputs)
#define NWG_ 250           // 256 outputs per block

typedef __attribute__((ext_vector_type(8))) _Float16 f16x8;
typedef __attribute__((ext_vector_type(2))) _Float16 f16x2;
typedef __attribute__((ext_vector_type(4))) float f32x4;

static __device__ __forceinline__ float dot2f(f16x2 a, f16x2 b, float c) {
#if __has_builtin(__builtin_amdgcn_fdot2)
  return __builtin_amdgcn_fdot2(a, b, c, false);
#else
  return fmaf((float)a[0], (float)b[0], fmaf((float)a[1], (float)b[1], c));
#endif
}

// ---------------- K0: merged fp64 prefix (16 blocks) + Toeplitz frag table (1038 blocks) ----------------
// FRAG[t][lane][j] = imp[(t-14)*16 + (lane&15) - 8*(lane>>4) - j]
__global__ __launch_bounds__(512) void k_pre(const float* __restrict__ pitch,
                                             const float* __restrict__ rn,
                                             const float* __restrict__ dec,
                                             const float* __restrict__ wet,
                                             double* __restrict__ Pv,
                                             double* __restrict__ Xv,
                                             _Float16* __restrict__ FH,
                                             _Float16* __restrict__ PH) {
  const int blk = blockIdx.x, tid = threadIdx.x;
  if (blk >= NT_) {
    // ---- prefix branch ----
    __shared__ double s[512];
    const int b = blk - NT_, t = tid;
    double x = 0.0;
    if (t < T_) x = (double)pitch[b * T_ + t] * (1.0 / (double)SR_);
    s[t] = x;
    __syncthreads();
    for (int off = 1; off < 512; off <<= 1) {
      double v = (t >= off) ? s[t - off] : 0.0;
      __syncthreads();
      s[t] += v;
      __syncthreads();
    }
    if (t < T_) {
      Xv[b * T_ + t] = x;
      Pv[b * T_ + t] = (s[t] - x) * 160.0;
    }
    return;
  }
  // ---- fragbuild branch ----
  const int t = blk;
  const int gid = t * 512 + tid;
  if (gid < 32256) ((f32x4*)PH)[gid] = (f32x4){0.f, 0.f, 0.f, 0.f};
  const int lane = tid >> 3, j = tid & 7;
  const int idx = (t - 14) * 16 + (lane & 15) - ((lane >> 4) << 3) - j;
  float v = 0.f;
  if (idx == 0) {
    v = 1.0f;
  } else if (idx > 0 && idx < REV_) {
    const float a = log1pf(expf(-dec[0]));
    const float sg = 1.f / (1.f + expf(-wet[0]));
    v = rn[idx] * expf(-a * ((float)idx / (float)SR_) * 500.0f) * sg;
  }
  FH[t * 512 + tid] = (_Float16)v;
}

// ---------------- K2: dual-column harmonic synth + filtered noise -> packed fp16 ----------------
// 320 threads = 5 full waves; group g in {0,1} handles bt = 2*blk+g with local tid ltid in [0,160).
__global__ __launch_bounds__(320) void k_synth(
    const float* __restrict__ pitch, const float* __restrict__ tamp,
    const float* __restrict__ harmo, const float* __restrict__ nfilt,
    const float* __restrict__ noise, const double* __restrict__ Pv,
    const double* __restrict__ Xv, _Float16* __restrict__ PH) {
  const int tid = threadIdx.x;
  const int g = (tid >= 160) ? 1 : 0;
  const int ltid = tid - (g << 7) - (g << 5);  // tid - 160*g
  const int bt = (blockIdx.x << 1) + g;
  const int b = bt / T_, t = bt - b * T_;
  __shared__ __align__(16) float amp[2][112];
  __shared__ __align__(16) float a_s[2][68];
  __shared__ __align__(16) float ir_s[2][68];
  __shared__ __align__(16) _Float16 C0[2][320];      // noi_pad (160 zeros + noise)
  __shared__ __align__(16) _Float16 C1[2][320];      // shifted copy: C1[x] = noi_pad[x+1]
  __shared__ __align__(16) _Float16 imp_sw[2][128];  // [0..63] segA, [64..127] segB, pair-swapped
  __shared__ float red_s[2];

  const float pv = pitch[bt];
  // n_valid: largest h (1-based) with fp32(h*pv) < 8000, capped at 100
  int nv = (int)(8000.0f / pv);
  if (nv > NH_) nv = NH_;
  while (nv < NH_ && (float)(nv + 1) * pv < 8000.0f) ++nv;
  while (nv > 0 && (float)nv * pv >= 8000.0f) --nv;

  // ---- phase A: loads/staging ----
  if (ltid < NB_) a_s[g][ltid] = nfilt[bt * NB_ + ltid];
  {
    const _Float16 nh = (_Float16)noise[bt * BLK_ + ltid];
    C0[g][160 + ltid] = nh;
    C1[g][159 + ltid] = nh;
    C0[g][ltid] = (_Float16)0.f;
    if (ltid < 159) C1[g][ltid] = (_Float16)0.f;
  }
  if (ltid < NH_) {
    const float ha = harmo[(b * NH_ + ltid) * T_ + t];
    const float aa = (pv * (float)(ltid + 1) < 8000.0f ? 1.0f : 0.0f) + 1e-4f;
    amp[g][ltid] = ha * aa;
  } else if (ltid < 112) {
    amp[g][ltid] = 0.f;
  }
  __syncthreads();  // B1

  // ---- phase B: 128-pt zero-phase irfft, symmetric half (i<=64), Chebyshev 4-strand ----
  float irv = 0.f;
  if (ltid < 65) {
    const float phi = (float)ltid * (1.0f / 128.0f);
    const float c1 = __builtin_amdgcn_cosf(phi);
    const float c2 = fmaf(2.f * c1, c1, -1.f);
    const float c3 = fmaf(2.f * c2, c1, -c1);
    const float c4 = fmaf(2.f * c2, c2, -1.f);
    const float tc = 2.f * c4;
    float x0 = 1.f, p0 = c4;
    float x1 = c1, p1 = c3;
    float x2 = c2, p2 = c2;
    float x3 = c3, p3 = c1;
    float a0 = 0.f, a1 = 0.f, a2 = 0.f, a3 = 0.f;
#pragma unroll
    for (int m = 0; m < 8; ++m) {
      const f32x4 aA = *(const f32x4*)&a_s[g][m << 3];
      const f32x4 aB = *(const f32x4*)&a_s[g][(m << 3) + 4];
      a0 = fmaf(aA[0], x0, a0); const float y0 = fmaf(tc, x0, -p0);
      a1 = fmaf(aA[1], x1, a1); const float y1 = fmaf(tc, x1, -p1);
      a2 = fmaf(aA[2], x2, a2); const float y2 = fmaf(tc, x2, -p2);
      a3 = fmaf(aA[3], x3, a3); const float y3 = fmaf(tc, x3, -p3);
      a0 = fmaf(aB[0], y0, a0); const float z0 = fmaf(tc, y0, -x0); p0 = y0; x0 = z0;
      a1 = fmaf(aB[1], y1, a1); const float z1 = fmaf(tc, y1, -x1); p1 = y1; x1 = z1;
      a2 = fmaf(aB[2], y2, a2); const float z2 = fmaf(tc, y2, -x2); p2 = y2; x2 = z2;
      a3 = fmaf(aB[3], y3, a3); const float z3 = fmaf(tc, y3, -x3); p3 = y3; x3 = z3;
    }
    const float accS = (a0 + a1) + (a2 + a3);
    irv = (2.f * accS - a_s[g][0] + ((ltid & 1) ? -a_s[g][64] : a_s[g][64])) * (1.0f / 128.0f);
    ir_s[g][ltid] = irv;
  } else if (ltid >= 128) {
    // 32 lanes: raw-amp sum via shuffle reduce (xor<=16 stays within 32-lane half)
    const int l = ltid - 128;
    float v = amp[g][l] + amp[g][l + 32] + amp[g][l + 64] + (l < 4 ? amp[g][l + 96] : 0.f);
    v += __shfl_xor(v, 16);
    v += __shfl_xor(v, 8);
    v += __shfl_xor(v, 4);
    v += __shfl_xor(v, 2);
    v += __shfl_xor(v, 1);
    if (l == 0) red_s[g] = v;
  }
  __syncthreads();  // B2

  // ---- phase C: windowed impulse (fp16, pair-swapped; uses ir symmetry), theta setup ----
  if (ltid < 64) {
    const float w = 0.5f + 0.5f * __builtin_amdgcn_cosf((float)ltid * (1.0f / 128.0f));
    imp_sw[g][ltid ^ 1] = (_Float16)(w * irv);
  } else if (ltid >= 96 && ltid < 160) {
    const int u = ltid - 96;
    const float w = 0.5f - 0.5f * __builtin_amdgcn_cosf((float)u * (1.0f / 128.0f));
    imp_sw[g][64 + (u ^ 1)] = (_Float16)(w * ir_s[g][64 - u]);
  }
  const float scale = tamp[bt] / red_s[g];
  double th = Pv[bt] + (double)(ltid + 1) * Xv[bt];
  th -= floor(th);
  const float theta = (float)th;
  const float cT = __builtin_amdgcn_cosf(theta);
  const float sT = __builtin_amdgcn_sinf(theta);
  __syncthreads();  // B3

  // ---- phase E1: harmonic additive synthesis, Chebyshev 4-strand ----
  float acc;
  {
    const float c2 = fmaf(cT, cT, -sT * sT);
    const float s2 = 2.f * cT * sT;
    const float s3 = fmaf(s2, cT, c2 * sT);
    const float s4 = 2.f * s2 * c2;
    const float c4 = fmaf(2.f * c2, c2, -1.f);
    const float tc = 2.f * c4;
    float x0 = sT, p0 = -s3;
    float x1 = s2, p1 = -s2;
    float x2 = s3, p2 = -sT;
    float x3 = s4, p3 = 0.f;
    float a0 = 0.f, a1 = 0.f, a2 = 0.f, a3 = 0.f;
    const int S = (nv + 7) >> 3;
    for (int m = 0; m < S; ++m) {
      const f32x4 aA = *(const f32x4*)&amp[g][m << 3];
      const f32x4 aB = *(const f32x4*)&amp[g][(m << 3) + 4];
      a0 = fmaf(aA[0], x0, a0); const float y0 = fmaf(tc, x0, -p0);
      a1 = fmaf(aA[1], x1, a1); const float y1 = fmaf(tc, x1, -p1);
      a2 = fmaf(aA[2], x2, a2); const float y2 = fmaf(tc, x2, -p2);
      a3 = fmaf(aA[3], x3, a3); const float y3 = fmaf(tc, x3, -p3);
      a0 = fmaf(aB[0], y0, a0); const float z0 = fmaf(tc, y0, -x0); p0 = y0; x0 = z0;
      a1 = fmaf(aB[1], y1, a1); const float z1 = fmaf(tc, y1, -x1); p1 = y1; x1 = z1;
      a2 = fmaf(aB[2], y2, a2); const float z2 = fmaf(tc, y2, -x2); p2 = y2; x2 = z2;
      a3 = fmaf(aB[3], y3, a3); const float z3 = fmaf(tc, y3, -x3); p3 = y3; x3 = z3;
    }
    acc = ((a0 + a1) + (a2 + a3)) * scale;
  }

  // ---- phase E2: 128-tap noise conv via packed fp16 dot2 ----
  float nf = 0.f;
  {
    const f16x2* np0;
    int pe;  // f16x2 pair index of the j=0 window
    if (ltid & 1) {
      np0 = (const f16x2*)C0[g];
      pe = (159 + ltid) >> 1;
    } else {
      np0 = (const f16x2*)C1[g];
      pe = (158 + ltid) >> 1;
    }
    const f16x8* ip = (const f16x8*)imp_sw[g];
#pragma unroll
    for (int k0 = 0; k0 < 8; ++k0) {  // segment A: j = 0..63
      const f16x8 i8 = ip[k0];
      const int kb = k0 << 2;
      nf = dot2f((f16x2){i8[0], i8[1]}, np0[pe - kb], nf);
      nf = dot2f((f16x2){i8[2], i8[3]}, np0[pe - kb - 1], nf);
      nf = dot2f((f16x2){i8[4], i8[5]}, np0[pe - kb - 2], nf);
      nf = dot2f((f16x2){i8[6], i8[7]}, np0[pe - kb - 3], nf);
    }
#pragma unroll
    for (int k0 = 0; k0 < 8; ++k0) {  // segment B: j = 96..159
      const f16x8 i8 = ip[8 + k0];
      const int kb = (k0 << 2) + 48;
      nf = dot2f((f16x2){i8[0], i8[1]}, np0[pe - kb], nf);
      nf = dot2f((f16x2){i8[2], i8[3]}, np0[pe - kb - 1], nf);
      nf = dot2f((f16x2){i8[4], i8[5]}, np0[pe - kb - 2], nf);
      nf = dot2f((f16x2){i8[6], i8[7]}, np0[pe - kb - 3], nf);
    }
  }

  const float v = acc + nf;
  const unsigned k = (unsigned)(KPAD_ + t * BLK_ + ltid);
  const unsigned off = ((k >> 3) << 7) + ((unsigned)b << 3) + (k & 7u);
  PH[off] = (_Float16)v;
}

// ---------------- K4: reverb Toeplitz MFMA GEMM, 2 M-halves x 4 K-quarters per block ----------------
static __device__ __forceinline__ f32x4 mfma_f16(f16x8 a, f16x8 b, f32x4 c) {
  return __builtin_amdgcn_mfma_f32_16x16x32_f16(a, b, c, 0, 0, 0);
}

template <int U, bool PF>
__device__ __forceinline__ void conv_step(f16x8 (&Rh)[M_], f32x4 (&acc)[M_], f16x8& bhi,
                                          const f16x8* __restrict__ ph,
                                          const f16x8* __restrict__ fh,
                                          int& kcur, int& tcur) {
  f16x8 nbh, na0, na1;
  if (PF) {
    kcur += 64;              // +32 samples = +64 f16x8 units
    nbh = ph[kcur];
    tcur -= 2;
    na0 = fh[tcur * 64];
    na1 = fh[(tcur + 1) * 64];
  }
#pragma unroll
  for (int m = 0; m < M_; ++m) {
    const int sl = (m - 2 * U) & (M_ - 1);
    acc[m] = mfma_f16(Rh[sl], bhi, acc[m]);
  }
  if (PF) {
    Rh[(M_ - 2 - 2 * U) & (M_ - 1)] = na0;
    Rh[(M_ - 1 - 2 * U) & (M_ - 1)] = na1;
    bhi = nbh;
  }
}

__global__ __launch_bounds__(512) void k_mconv(const f16x8* __restrict__ FH,
                                               const f16x8* __restrict__ PH,
                                               float* __restrict__ out) {
  const int tid = threadIdx.x;
  const int s = tid >> 6, lane = tid & 63;
  const int mw = s & 1, kw = s >> 1;        // M-half, K-quarter
  int w = blockIdx.x;
  {  // bijective XCD swizzle, nwg=250 (q=31, r=2)
    const int q = NWG_ / 8, r = NWG_ % 8;
    const int xcd = w & 7, o = w >> 3;
    w = (xcd < r ? xcd * (q + 1) : r * (q + 1) + (xcd - r) * q) + o;
  }
  const int Q0 = w << 8;                    // 256 outputs per block
  const int T0 = 1022 + (mw << 3) - (kw << 8);  // frag-table index at step 0, m=0

  const f16x8* fh = FH + lane;
  f16x8 Rh[M_];
#pragma unroll
  for (int m = 0; m < M_; ++m) Rh[m] = fh[(T0 + m) * 64];
  f32x4 acc[M_];
#pragma unroll
  for (int m = 0; m < M_; ++m) acc[m] = (f32x4){0.f, 0.f, 0.f, 0.f};

  const f16x8* ph = PH + ((lane >> 4) << 4) + (lane & 15);
  int kcur = (Q0 + (kw << 12)) << 1;        // padded-sample*2 unit index; B shared by both mw
  int tcur = T0;
  f16x8 bhi = ph[kcur];

  for (int ii = 0; ii < 31; ++ii) {         // steps 0..123
    conv_step<0, true>(Rh, acc, bhi, ph, fh, kcur, tcur);
    conv_step<1, true>(Rh, acc, bhi, ph, fh, kcur, tcur);
    conv_step<2, true>(Rh, acc, bhi, ph, fh, kcur, tcur);
    conv_step<3, true>(Rh, acc, bhi, ph, fh, kcur, tcur);
    __builtin_amdgcn_s_barrier();           // keep mw-pair in lockstep for L1 A/B reuse
  }
  conv_step<0, true>(Rh, acc, bhi, ph, fh, kcur, tcur);    // 124
  conv_step<1, true>(Rh, acc, bhi, ph, fh, kcur, tcur);    // 125
  conv_step<2, true>(Rh, acc, bhi, ph, fh, kcur, tcur);    // 126
  conv_step<3, false>(Rh, acc, bhi, ph, fh, kcur, tcur);   // 127

  // cross-wave K-quarter reduction in LDS, then coalesced stores
  __shared__ f32x4 part[8][M_][64];
#pragma unroll
  for (int m = 0; m < M_; ++m) part[s][m][lane] = acc[m];
  __syncthreads();
#pragma unroll
  for (int half = 0; half < 2; ++half) {
    const int it = tid + (half << 9);
    const int ln = it & 63, m = (it >> 6) & 7, mwi = it >> 9;
    f32x4 v = part[mwi][m][ln];
    v += part[mwi + 2][m][ln];
    v += part[mwi + 4][m][ln];
    v += part[mwi + 6][m][ln];
    const int b = ln & 15, gq = ln >> 4;
    *(f32x4*)(out + (size_t)b * N_ + Q0 + (mwi << 7) + (m << 4) + (gq << 2)) = v;
  }
}

extern "C" void kernel_launch(void* const* d_in, const int* in_sizes, int n_in,
                              void* d_out, int out_size, void* d_ws, size_t ws_size,
                              hipStream_t stream) {
  const float* pitch = (const float*)d_in[0];
  const float* tamp  = (const float*)d_in[1];
  const float* harmo = (const float*)d_in[2];
  const float* nfilt = (const float*)d_in[3];
  const float* noise = (const float*)d_in[4];
  const float* rn    = (const float*)d_in[5];
  const float* dec   = (const float*)d_in[6];
  const float* wet   = (const float*)d_in[7];

  char* ws = (char*)d_ws;
  size_t off = 0;
  _Float16* PH = (_Float16*)(ws + off); off += (size_t)KTOT_ * 16 * 2;   // 2.56 MB
  _Float16* FH = (_Float16*)(ws + off); off += (size_t)NT_ * 512 * 2;    // 1.06 MB
  double* Pv = (double*)(ws + off);     off += (size_t)B_ * T_ * 8;
  double* Xv = (double*)(ws + off);     off += (size_t)B_ * T_ * 8;
  float* out = (float*)d_out;

  k_pre<<<dim3(NT_ + B_), dim3(512), 0, stream>>>(pitch, rn, dec, wet, Pv, Xv, FH, PH);
  k_synth<<<dim3(B_ * T_ / 2), dim3(320), 0, stream>>>(pitch, tamp, harmo, nfilt, noise, Pv, Xv, PH);
  k_mconv<<<dim3(NWG_), dim3(512), 0, stream>>>((const f16x8*)FH, (const f16x8*)PH, out);
}

// Round 10
// 60.825 us; speedup vs baseline: 2.8940x; 1.1222x over previous
//
#include <hip/hip_runtime.h>

#define B_ 16
#define T_ 400
#define NH_ 100
#define NB_ 65
#define BLK_ 160
#define SR_ 16000
#define N_ 64000           // T_*BLK_
#define REV_ 16000
#define KPAD_ 16128        // front zero pad of signal
#define KTOT_ 80128        // KPAD_ + N_
#define NT_ 1038           // Toeplitz frag table entries, t in [0,1038)
#define M_ 16              // m-tiles per wave (256 outputs)
#define NWG_ 250           // 256 outputs per block

typedef __attribute__((ext_vector_type(8))) _Float16 f16x8;
typedef __attribute__((ext_vector_type(2))) _Float16 f16x2;
typedef __attribute__((ext_vector_type(4))) float f32x4;

static __device__ __forceinline__ float dot2f(f16x2 a, f16x2 b, float c) {
#if __has_builtin(__builtin_amdgcn_fdot2)
  return __builtin_amdgcn_fdot2(a, b, c, false);
#else
  return fmaf((float)a[0], (float)b[0], fmaf((float)a[1], (float)b[1], c));
#endif
}

// ---------------- K0: merged fp64 prefix (16 blocks) + Toeplitz frag table (1038 blocks) ----------------
// FRAG[t][lane][j] = imp[(t-14)*16 + (lane&15) - 8*(lane>>4) - j]
__global__ __launch_bounds__(512) void k_pre(const float* __restrict__ pitch,
                                             const float* __restrict__ rn,
                                             const float* __restrict__ dec,
                                             const float* __restrict__ wet,
                                             double* __restrict__ Pv,
                                             double* __restrict__ Xv,
                                             _Float16* __restrict__ FH,
                                             _Float16* __restrict__ PH) {
  const int blk = blockIdx.x, tid = threadIdx.x;
  if (blk >= NT_) {
    // ---- prefix branch ----
    __shared__ double s[512];
    const int b = blk - NT_, t = tid;
    double x = 0.0;
    if (t < T_) x = (double)pitch[b * T_ + t] * (1.0 / (double)SR_);
    s[t] = x;
    __syncthreads();
    for (int off = 1; off < 512; off <<= 1) {
      double v = (t >= off) ? s[t - off] : 0.0;
      __syncthreads();
      s[t] += v;
      __syncthreads();
    }
    if (t < T_) {
      Xv[b * T_ + t] = x;
      Pv[b * T_ + t] = (s[t] - x) * 160.0;
    }
    return;
  }
  // ---- fragbuild branch ----
  const int t = blk;
  const int gid = t * 512 + tid;
  if (gid < 32256) ((f32x4*)PH)[gid] = (f32x4){0.f, 0.f, 0.f, 0.f};
  const int lane = tid >> 3, j = tid & 7;
  const int idx = (t - 14) * 16 + (lane & 15) - ((lane >> 4) << 3) - j;
  float v = 0.f;
  if (idx == 0) {
    v = 1.0f;
  } else if (idx > 0 && idx < REV_) {
    const float a = log1pf(expf(-dec[0]));
    const float sg = 1.f / (1.f + expf(-wet[0]));
    v = rn[idx] * expf(-a * ((float)idx / (float)SR_) * 500.0f) * sg;
  }
  FH[t * 512 + tid] = (_Float16)v;
}

// ---------------- K2: dual-column harmonic synth + filtered noise -> packed fp16 ----------------
// 320 threads = 5 full waves; group g in {0,1} handles bt = 2*blk+g with local tid ltid in [0,160).
__global__ __launch_bounds__(320) void k_synth(
    const float* __restrict__ pitch, const float* __restrict__ tamp,
    const float* __restrict__ harmo, const float* __restrict__ nfilt,
    const float* __restrict__ noise, const double* __restrict__ Pv,
    const double* __restrict__ Xv, _Float16* __restrict__ PH) {
  const int tid = threadIdx.x;
  const int g = (tid >= 160) ? 1 : 0;
  const int ltid = tid - (g << 7) - (g << 5);  // tid - 160*g
  const int bt = (blockIdx.x << 1) + g;
  const int b = bt / T_, t = bt - b * T_;
  __shared__ __align__(16) float amp[2][112];
  __shared__ __align__(16) float a_s[2][68];
  __shared__ __align__(16) float ir_s[2][68];
  __shared__ __align__(16) _Float16 C0[2][320];      // noi_pad (160 zeros + noise)
  __shared__ __align__(16) _Float16 C1[2][320];      // shifted copy: C1[x] = noi_pad[x+1]
  __shared__ __align__(16) _Float16 imp_sw[2][128];  // [0..63] segA, [64..127] segB, pair-swapped
  __shared__ float red_s[2];

  const float pv = pitch[bt];
  // n_valid: largest h (1-based) with fp32(h*pv) < 8000, capped at 100
  int nv = (int)(8000.0f / pv);
  if (nv > NH_) nv = NH_;
  while (nv < NH_ && (float)(nv + 1) * pv < 8000.0f) ++nv;
  while (nv > 0 && (float)nv * pv >= 8000.0f) --nv;

  // ---- phase A: loads/staging ----
  if (ltid < NB_) a_s[g][ltid] = nfilt[bt * NB_ + ltid];
  {
    const _Float16 nh = (_Float16)noise[bt * BLK_ + ltid];
    C0[g][160 + ltid] = nh;
    C1[g][159 + ltid] = nh;
    C0[g][ltid] = (_Float16)0.f;
    if (ltid < 159) C1[g][ltid] = (_Float16)0.f;
  }
  if (ltid < NH_) {
    const float ha = harmo[(b * NH_ + ltid) * T_ + t];
    const float aa = (pv * (float)(ltid + 1) < 8000.0f ? 1.0f : 0.0f) + 1e-4f;
    amp[g][ltid] = ha * aa;
  } else if (ltid < 112) {
    amp[g][ltid] = 0.f;
  }
  __syncthreads();  // B1

  // ---- phase B: 128-pt zero-phase irfft, symmetric half (i<=64), Chebyshev 4-strand ----
  float irv = 0.f;
  if (ltid < 65) {
    const float phi = (float)ltid * (1.0f / 128.0f);
    const float c1 = __builtin_amdgcn_cosf(phi);
    const float c2 = fmaf(2.f * c1, c1, -1.f);
    const float c3 = fmaf(2.f * c2, c1, -c1);
    const float c4 = fmaf(2.f * c2, c2, -1.f);
    const float tc = 2.f * c4;
    float x0 = 1.f, p0 = c4;
    float x1 = c1, p1 = c3;
    float x2 = c2, p2 = c2;
    float x3 = c3, p3 = c1;
    float a0 = 0.f, a1 = 0.f, a2 = 0.f, a3 = 0.f;
#pragma unroll
    for (int m = 0; m < 8; ++m) {
      const f32x4 aA = *(const f32x4*)&a_s[g][m << 3];
      const f32x4 aB = *(const f32x4*)&a_s[g][(m << 3) + 4];
      a0 = fmaf(aA[0], x0, a0); const float y0 = fmaf(tc, x0, -p0);
      a1 = fmaf(aA[1], x1, a1); const float y1 = fmaf(tc, x1, -p1);
      a2 = fmaf(aA[2], x2, a2); const float y2 = fmaf(tc, x2, -p2);
      a3 = fmaf(aA[3], x3, a3); const float y3 = fmaf(tc, x3, -p3);
      a0 = fmaf(aB[0], y0, a0); const float z0 = fmaf(tc, y0, -x0); p0 = y0; x0 = z0;
      a1 = fmaf(aB[1], y1, a1); const float z1 = fmaf(tc, y1, -x1); p1 = y1; x1 = z1;
      a2 = fmaf(aB[2], y2, a2); const float z2 = fmaf(tc, y2, -x2); p2 = y2; x2 = z2;
      a3 = fmaf(aB[3], y3, a3); const float z3 = fmaf(tc, y3, -x3); p3 = y3; x3 = z3;
    }
    const float accS = (a0 + a1) + (a2 + a3);
    irv = (2.f * accS - a_s[g][0] + ((ltid & 1) ? -a_s[g][64] : a_s[g][64])) * (1.0f / 128.0f);
    ir_s[g][ltid] = irv;
  } else if (ltid >= 128) {
    // 32 lanes: raw-amp sum via shuffle reduce (xor<=16 stays within 32-lane half)
    const int l = ltid - 128;
    float v = amp[g][l] + amp[g][l + 32] + amp[g][l + 64] + (l < 4 ? amp[g][l + 96] : 0.f);
    v += __shfl_xor(v, 16);
    v += __shfl_xor(v, 8);
    v += __shfl_xor(v, 4);
    v += __shfl_xor(v, 2);
    v += __shfl_xor(v, 1);
    if (l == 0) red_s[g] = v;
  }
  __syncthreads();  // B2

  // ---- phase C: windowed impulse (fp16, pair-swapped; uses ir symmetry), theta setup ----
  if (ltid < 64) {
    const float w = 0.5f + 0.5f * __builtin_amdgcn_cosf((float)ltid * (1.0f / 128.0f));
    imp_sw[g][ltid ^ 1] = (_Float16)(w * irv);
  } else if (ltid >= 96 && ltid < 160) {
    const int u = ltid - 96;
    const float w = 0.5f - 0.5f * __builtin_amdgcn_cosf((float)u * (1.0f / 128.0f));
    imp_sw[g][64 + (u ^ 1)] = (_Float16)(w * ir_s[g][64 - u]);
  }
  const float scale = tamp[bt] / red_s[g];
  double th = Pv[bt] + (double)(ltid + 1) * Xv[bt];
  th -= floor(th);
  const float theta = (float)th;
  const float cT = __builtin_amdgcn_cosf(theta);
  const float sT = __builtin_amdgcn_sinf(theta);
  __syncthreads();  // B3

  // ---- phase E1: harmonic additive synthesis, Chebyshev 4-strand ----
  float acc;
  {
    const float c2 = fmaf(cT, cT, -sT * sT);
    const float s2 = 2.f * cT * sT;
    const float s3 = fmaf(s2, cT, c2 * sT);
    const float s4 = 2.f * s2 * c2;
    const float c4 = fmaf(2.f * c2, c2, -1.f);
    const float tc = 2.f * c4;
    float x0 = sT, p0 = -s3;
    float x1 = s2, p1 = -s2;
    float x2 = s3, p2 = -sT;
    float x3 = s4, p3 = 0.f;
    float a0 = 0.f, a1 = 0.f, a2 = 0.f, a3 = 0.f;
    const int S = (nv + 7) >> 3;
    for (int m = 0; m < S; ++m) {
      const f32x4 aA = *(const f32x4*)&amp[g][m << 3];
      const f32x4 aB = *(const f32x4*)&amp[g][(m << 3) + 4];
      a0 = fmaf(aA[0], x0, a0); const float y0 = fmaf(tc, x0, -p0);
      a1 = fmaf(aA[1], x1, a1); const float y1 = fmaf(tc, x1, -p1);
      a2 = fmaf(aA[2], x2, a2); const float y2 = fmaf(tc, x2, -p2);
      a3 = fmaf(aA[3], x3, a3); const float y3 = fmaf(tc, x3, -p3);
      a0 = fmaf(aB[0], y0, a0); const float z0 = fmaf(tc, y0, -x0); p0 = y0; x0 = z0;
      a1 = fmaf(aB[1], y1, a1); const float z1 = fmaf(tc, y1, -x1); p1 = y1; x1 = z1;
      a2 = fmaf(aB[2], y2, a2); const float z2 = fmaf(tc, y2, -x2); p2 = y2; x2 = z2;
      a3 = fmaf(aB[3], y3, a3); const float z3 = fmaf(tc, y3, -x3); p3 = y3; x3 = z3;
    }
    acc = ((a0 + a1) + (a2 + a3)) * scale;
  }

  // ---- phase E2: 128-tap noise conv via packed fp16 dot2 ----
  float nf = 0.f;
  {
    const f16x2* np0;
    int pe;  // f16x2 pair index of the j=0 window
    if (ltid & 1) {
      np0 = (const f16x2*)C0[g];
      pe = (159 + ltid) >> 1;
    } else {
      np0 = (const f16x2*)C1[g];
      pe = (158 + ltid) >> 1;
    }
    const f16x8* ip = (const f16x8*)imp_sw[g];
#pragma unroll
    for (int k0 = 0; k0 < 8; ++k0) {  // segment A: j = 0..63
      const f16x8 i8 = ip[k0];
      const int kb = k0 << 2;
      nf = dot2f((f16x2){i8[0], i8[1]}, np0[pe - kb], nf);
      nf = dot2f((f16x2){i8[2], i8[3]}, np0[pe - kb - 1], nf);
      nf = dot2f((f16x2){i8[4], i8[5]}, np0[pe - kb - 2], nf);
      nf = dot2f((f16x2){i8[6], i8[7]}, np0[pe - kb - 3], nf);
    }
#pragma unroll
    for (int k0 = 0; k0 < 8; ++k0) {  // segment B: j = 96..159
      const f16x8 i8 = ip[8 + k0];
      const int kb = (k0 << 2) + 48;
      nf = dot2f((f16x2){i8[0], i8[1]}, np0[pe - kb], nf);
      nf = dot2f((f16x2){i8[2], i8[3]}, np0[pe - kb - 1], nf);
      nf = dot2f((f16x2){i8[4], i8[5]}, np0[pe - kb - 2], nf);
      nf = dot2f((f16x2){i8[6], i8[7]}, np0[pe - kb - 3], nf);
    }
  }

  const float v = acc + nf;
  const unsigned k = (unsigned)(KPAD_ + t * BLK_ + ltid);
  const unsigned off = ((k >> 3) << 7) + ((unsigned)b << 3) + (k & 7u);
  PH[off] = (_Float16)v;
}

// ---------------- K4: reverb Toeplitz MFMA GEMM, M=16 ring, depth-2 prefetch ----------------
static __device__ __forceinline__ f32x4 mfma_f16(f16x8 a, f16x8 b, f32x4 c) {
  return __builtin_amdgcn_mfma_f32_16x16x32_f16(a, b, c, 0, 0, 0);
}

template <int U, bool ISSUE, bool CONSUME>
__device__ __forceinline__ void conv_step(f16x8 (&Rh)[M_], f32x4 (&acc)[M_], f16x8& bhi,
                                          f16x8 (&nb)[2], f16x8 (&na0)[2], f16x8 (&na1)[2],
                                          const f16x8* __restrict__ ph,
                                          const f16x8* __restrict__ fh,
                                          int& kit, int& tit) {
  if (ISSUE) {  // loads for step U+2 (double-buffered, static parity U&1)
    kit += 64;               // +32 samples = +64 f16x8 units
    nb[U & 1] = ph[kit];
    tit -= 2;
    na0[U & 1] = fh[tit * 64];
    na1[U & 1] = fh[(tit + 1) * 64];
  }
#pragma unroll
  for (int m = 0; m < M_; ++m) {
    const int sl = (m - 2 * U) & (M_ - 1);
    acc[m] = mfma_f16(Rh[sl], bhi, acc[m]);
  }
  if (CONSUME) {  // install data for step U+1 (issued at step U-1, parity (U+1)&1)
    Rh[(M_ - 2 - 2 * U) & (M_ - 1)] = na0[(U + 1) & 1];
    Rh[(M_ - 1 - 2 * U) & (M_ - 1)] = na1[(U + 1) & 1];
    bhi = nb[(U + 1) & 1];
  }
}

__global__ __launch_bounds__(512) void k_mconv(const f16x8* __restrict__ FH,
                                               const f16x8* __restrict__ PH,
                                               float* __restrict__ out) {
  const int tid = threadIdx.x;
  const int s = tid >> 6, lane = tid & 63;
  int w = blockIdx.x;
  {  // bijective XCD swizzle, nwg=250 (q=31, r=2)
    const int q = NWG_ / 8, r = NWG_ % 8;
    const int xcd = w & 7, o = w >> 3;
    w = (xcd < r ? xcd * (q + 1) : r * (q + 1) + (xcd - r) * q) + o;
  }
  const int Q0 = w << 8;                    // 256 outputs per block
  const int T0 = 1022 - 128 * s;            // frag-table index at step 0, m=0 (r4-verified)

  const f16x8* fh = FH + lane;
  f16x8 Rh[M_];
#pragma unroll
  for (int m = 0; m < M_; ++m) Rh[m] = fh[(T0 + m) * 64];
  f32x4 acc[M_];
#pragma unroll
  for (int m = 0; m < M_; ++m) acc[m] = (f32x4){0.f, 0.f, 0.f, 0.f};

  const f16x8* ph = PH + ((lane >> 4) << 4) + (lane & 15);
  int kit = (Q0 + 2048 * s) << 1;           // unit index (r4-verified)
  int tit = T0;
  f16x8 bhi = ph[kit];
  f16x8 nb[2], na0[2], na1[2];
  // prologue: issue step-1 data into parity-1 buffers
  kit += 64;
  nb[1] = ph[kit];
  tit -= 2;
  na0[1] = fh[tit * 64];
  na1[1] = fh[(tit + 1) * 64];

  for (int ii = 0; ii < 7; ++ii) {          // steps 0..55
    conv_step<0, true, true>(Rh, acc, bhi, nb, na0, na1, ph, fh, kit, tit);
    conv_step<1, true, true>(Rh, acc, bhi, nb, na0, na1, ph, fh, kit, tit);
    conv_step<2, true, true>(Rh, acc, bhi, nb, na0, na1, ph, fh, kit, tit);
    conv_step<3, true, true>(Rh, acc, bhi, nb, na0, na1, ph, fh, kit, tit);
    conv_step<4, true, true>(Rh, acc, bhi, nb, na0, na1, ph, fh, kit, tit);
    conv_step<5, true, true>(Rh, acc, bhi, nb, na0, na1, ph, fh, kit, tit);
    conv_step<6, true, true>(Rh, acc, bhi, nb, na0, na1, ph, fh, kit, tit);
    conv_step<7, true, true>(Rh, acc, bhi, nb, na0, na1, ph, fh, kit, tit);
  }
  conv_step<0, true, true>(Rh, acc, bhi, nb, na0, na1, ph, fh, kit, tit);   // 56
  conv_step<1, true, true>(Rh, acc, bhi, nb, na0, na1, ph, fh, kit, tit);   // 57
  conv_step<2, true, true>(Rh, acc, bhi, nb, na0, na1, ph, fh, kit, tit);   // 58
  conv_step<3, true, true>(Rh, acc, bhi, nb, na0, na1, ph, fh, kit, tit);   // 59
  conv_step<4, true, true>(Rh, acc, bhi, nb, na0, na1, ph, fh, kit, tit);   // 60
  conv_step<5, true, true>(Rh, acc, bhi, nb, na0, na1, ph, fh, kit, tit);   // 61
  conv_step<6, false, true>(Rh, acc, bhi, nb, na0, na1, ph, fh, kit, tit);  // 62
  conv_step<7, false, false>(Rh, acc, bhi, nb, na0, na1, ph, fh, kit, tit); // 63

  // two-stage cross-wave (K-split) reduction in LDS, then coalesced stores (r4-verified)
  __shared__ f32x4 part[4][M_][64];
  if (s < 4) {
#pragma unroll
    for (int m = 0; m < M_; ++m) part[s][m][lane] = acc[m];
  }
  __syncthreads();
  if (s >= 4) {
#pragma unroll
    for (int m = 0; m < M_; ++m) part[s - 4][m][lane] += acc[m];
  }
  __syncthreads();
#pragma unroll
  for (int half = 0; half < 2; ++half) {
    const int it = tid + (half << 9);
    const int m = it >> 6, ln = it & 63;
    f32x4 v = part[0][m][ln];
    v += part[1][m][ln];
    v += part[2][m][ln];
    v += part[3][m][ln];
    const int b = ln & 15, gq = ln >> 4;
    *(f32x4*)(out + (size_t)b * N_ + Q0 + (m << 4) + (gq << 2)) = v;
  }
}

extern "C" void kernel_launch(void* const* d_in, const int* in_sizes, int n_in,
                              void* d_out, int out_size, void* d_ws, size_t ws_size,
                              hipStream_t stream) {
  const float* pitch = (const float*)d_in[0];
  const float* tamp  = (const float*)d_in[1];
  const float* harmo = (const float*)d_in[2];
  const float* nfilt = (const float*)d_in[3];
  const float* noise = (const float*)d_in[4];
  const float* rn    = (const float*)d_in[5];
  const float* dec   = (const float*)d_in[6];
  const float* wet   = (const float*)d_in[7];

  char* ws = (char*)d_ws;
  size_t off = 0;
  _Float16* PH = (_Float16*)(ws + off); off += (size_t)KTOT_ * 16 * 2;   // 2.56 MB
  _Float16* FH = (_Float16*)(ws + off); off += (size_t)NT_ * 512 * 2;    // 1.06 MB
  double* Pv = (double*)(ws + off);     off += (size_t)B_ * T_ * 8;
  double* Xv = (double*)(ws + off);     off += (size_t)B_ * T_ * 8;
  float* out = (float*)d_out;

  k_pre<<<dim3(NT_ + B_), dim3(512), 0, stream>>>(pitch, rn, dec, wet, Pv, Xv, FH, PH);
  k_synth<<<dim3(B_ * T_ / 2), dim3(320), 0, stream>>>(pitch, tamp, harmo, nfilt, noise, Pv, Xv, PH);
  k_mconv<<<dim3(NWG_), dim3(512), 0, stream>>>((const f16x8*)FH, (const f16x8*)PH, out);
}

// Round 11
// 58.887 us; speedup vs baseline: 2.9892x; 1.0329x over previous
//
#include <hip/hip_runtime.h>

#define B_ 16
#define T_ 400
#define NH_ 100
#define NB_ 65
#define BLK_ 160
#define SR_ 16000
#define N_ 64000           // T_*BLK_
#define REV_ 16000
#define KPAD_ 16128        // front zero pad of signal
#define KTOT_ 80128        // KPAD_ + N_
#define M_ 16              // m-tiles per wave (256 outputs)
#define NWG_ 250           // 256 outputs per block
#define ISTRIDE_ 16768     // elems per IMPREV copy (valid span 16704)

typedef __attribute__((ext_vector_type(8))) _Float16 f16x8;
typedef __attribute__((ext_vector_type(2))) _Float16 f16x2;
typedef __attribute__((ext_vector_type(4))) float f32x4;

static __device__ __forceinline__ float dot2f(f16x2 a, f16x2 b, float c) {
#if __has_builtin(__builtin_amdgcn_fdot2)
  return __builtin_amdgcn_fdot2(a, b, c, false);
#else
  return fmaf((float)a[0], (float)b[0], fmaf((float)a[1], (float)b[1], c));
#endif
}

// ---------------- K0: merged IMPREV build (66 blk) + PH front-pad zero (63) + fp64 prefix (16) ----------------
// IMPREV[c][u] = imp[16383 - u - c] (0 outside [0,REV_)), imp[0]=1.
__global__ __launch_bounds__(512) void k_pre(const float* __restrict__ pitch,
                                             const float* __restrict__ rn,
                                             const float* __restrict__ dec,
                                             const float* __restrict__ wet,
                                             double* __restrict__ Pv,
                                             double* __restrict__ Xv,
                                             _Float16* __restrict__ IMPREV,
                                             _Float16* __restrict__ PH) {
  const int blk = blockIdx.x, tid = threadIdx.x;
  if (blk < 66) {
    const int gid = blk * 512 + tid;
    if (gid < 2 * ISTRIDE_) {
      const int c = gid / ISTRIDE_, u = gid - c * ISTRIDE_;
      const int i = 16383 - u - c;
      float v = 0.f;
      if (i == 0) {
        v = 1.0f;
      } else if (i > 0 && i < REV_) {
        const float a = log1pf(expf(-dec[0]));
        const float sg = 1.f / (1.f + expf(-wet[0]));
        v = rn[i] * expf(-a * ((float)i / (float)SR_) * 500.0f) * sg;
      }
      IMPREV[gid] = (_Float16)v;
    }
    return;
  }
  if (blk < 129) {
    const int gid = (blk - 66) * 512 + tid;   // < 32256
    ((f32x4*)PH)[gid] = (f32x4){0.f, 0.f, 0.f, 0.f};
    return;
  }
  // ---- prefix branch ----
  __shared__ double s[512];
  const int b = blk - 129, t = tid;
  double x = 0.0;
  if (t < T_) x = (double)pitch[b * T_ + t] * (1.0 / (double)SR_);
  s[t] = x;
  __syncthreads();
  for (int off = 1; off < 512; off <<= 1) {
    double v = (t >= off) ? s[t - off] : 0.0;
    __syncthreads();
    s[t] += v;
    __syncthreads();
  }
  if (t < T_) {
    Xv[b * T_ + t] = x;
    Pv[b * T_ + t] = (s[t] - x) * 160.0;
  }
}

// ---------------- K2: dual-column harmonic synth + filtered noise -> packed fp16 (r8-identical) ----------------
__global__ __launch_bounds__(320) void k_synth(
    const float* __restrict__ pitch, const float* __restrict__ tamp,
    const float* __restrict__ harmo, const float* __restrict__ nfilt,
    const float* __restrict__ noise, const double* __restrict__ Pv,
    const double* __restrict__ Xv, _Float16* __restrict__ PH) {
  const int tid = threadIdx.x;
  const int g = (tid >= 160) ? 1 : 0;
  const int ltid = tid - (g << 7) - (g << 5);  // tid - 160*g
  const int bt = (blockIdx.x << 1) + g;
  const int b = bt / T_, t = bt - b * T_;
  __shared__ __align__(16) float amp[2][112];
  __shared__ __align__(16) float a_s[2][68];
  __shared__ __align__(16) float ir_s[2][68];
  __shared__ __align__(16) _Float16 C0[2][320];
  __shared__ __align__(16) _Float16 C1[2][320];
  __shared__ __align__(16) _Float16 imp_sw[2][128];
  __shared__ float red_s[2];

  const float pv = pitch[bt];
  int nv = (int)(8000.0f / pv);
  if (nv > NH_) nv = NH_;
  while (nv < NH_ && (float)(nv + 1) * pv < 8000.0f) ++nv;
  while (nv > 0 && (float)nv * pv >= 8000.0f) --nv;

  if (ltid < NB_) a_s[g][ltid] = nfilt[bt * NB_ + ltid];
  {
    const _Float16 nh = (_Float16)noise[bt * BLK_ + ltid];
    C0[g][160 + ltid] = nh;
    C1[g][159 + ltid] = nh;
    C0[g][ltid] = (_Float16)0.f;
    if (ltid < 159) C1[g][ltid] = (_Float16)0.f;
  }
  if (ltid < NH_) {
    const float ha = harmo[(b * NH_ + ltid) * T_ + t];
    const float aa = (pv * (float)(ltid + 1) < 8000.0f ? 1.0f : 0.0f) + 1e-4f;
    amp[g][ltid] = ha * aa;
  } else if (ltid < 112) {
    amp[g][ltid] = 0.f;
  }
  __syncthreads();  // B1

  float irv = 0.f;
  if (ltid < 65) {
    const float phi = (float)ltid * (1.0f / 128.0f);
    const float c1 = __builtin_amdgcn_cosf(phi);
    const float c2 = fmaf(2.f * c1, c1, -1.f);
    const float c3 = fmaf(2.f * c2, c1, -c1);
    const float c4 = fmaf(2.f * c2, c2, -1.f);
    const float tc = 2.f * c4;
    float x0 = 1.f, p0 = c4;
    float x1 = c1, p1 = c3;
    float x2 = c2, p2 = c2;
    float x3 = c3, p3 = c1;
    float a0 = 0.f, a1 = 0.f, a2 = 0.f, a3 = 0.f;
#pragma unroll
    for (int m = 0; m < 8; ++m) {
      const f32x4 aA = *(const f32x4*)&a_s[g][m << 3];
      const f32x4 aB = *(const f32x4*)&a_s[g][(m << 3) + 4];
      a0 = fmaf(aA[0], x0, a0); const float y0 = fmaf(tc, x0, -p0);
      a1 = fmaf(aA[1], x1, a1); const float y1 = fmaf(tc, x1, -p1);
      a2 = fmaf(aA[2], x2, a2); const float y2 = fmaf(tc, x2, -p2);
      a3 = fmaf(aA[3], x3, a3); const float y3 = fmaf(tc, x3, -p3);
      a0 = fmaf(aB[0], y0, a0); const float z0 = fmaf(tc, y0, -x0); p0 = y0; x0 = z0;
      a1 = fmaf(aB[1], y1, a1); const float z1 = fmaf(tc, y1, -x1); p1 = y1; x1 = z1;
      a2 = fmaf(aB[2], y2, a2); const float z2 = fmaf(tc, y2, -x2); p2 = y2; x2 = z2;
      a3 = fmaf(aB[3], y3, a3); const float z3 = fmaf(tc, y3, -x3); p3 = y3; x3 = z3;
    }
    const float accS = (a0 + a1) + (a2 + a3);
    irv = (2.f * accS - a_s[g][0] + ((ltid & 1) ? -a_s[g][64] : a_s[g][64])) * (1.0f / 128.0f);
    ir_s[g][ltid] = irv;
  } else if (ltid >= 128) {
    const int l = ltid - 128;
    float v = amp[g][l] + amp[g][l + 32] + amp[g][l + 64] + (l < 4 ? amp[g][l + 96] : 0.f);
    v += __shfl_xor(v, 16);
    v += __shfl_xor(v, 8);
    v += __shfl_xor(v, 4);
    v += __shfl_xor(v, 2);
    v += __shfl_xor(v, 1);
    if (l == 0) red_s[g] = v;
  }
  __syncthreads();  // B2

  if (ltid < 64) {
    const float w = 0.5f + 0.5f * __builtin_amdgcn_cosf((float)ltid * (1.0f / 128.0f));
    imp_sw[g][ltid ^ 1] = (_Float16)(w * irv);
  } else if (ltid >= 96 && ltid < 160) {
    const int u = ltid - 96;
    const float w = 0.5f - 0.5f * __builtin_amdgcn_cosf((float)u * (1.0f / 128.0f));
    imp_sw[g][64 + (u ^ 1)] = (_Float16)(w * ir_s[g][64 - u]);
  }
  const float scale = tamp[bt] / red_s[g];
  double th = Pv[bt] + (double)(ltid + 1) * Xv[bt];
  th -= floor(th);
  const float theta = (float)th;
  const float cT = __builtin_amdgcn_cosf(theta);
  const float sT = __builtin_amdgcn_sinf(theta);
  __syncthreads();  // B3

  float acc;
  {
    const float c2 = fmaf(cT, cT, -sT * sT);
    const float s2 = 2.f * cT * sT;
    const float s3 = fmaf(s2, cT, c2 * sT);
    const float s4 = 2.f * s2 * c2;
    const float c4 = fmaf(2.f * c2, c2, -1.f);
    const float tc = 2.f * c4;
    float x0 = sT, p0 = -s3;
    float x1 = s2, p1 = -s2;
    float x2 = s3, p2 = -sT;
    float x3 = s4, p3 = 0.f;
    float a0 = 0.f, a1 = 0.f, a2 = 0.f, a3 = 0.f;
    const int S = (nv + 7) >> 3;
    for (int m = 0; m < S; ++m) {
      const f32x4 aA = *(const f32x4*)&amp[g][m << 3];
      const f32x4 aB = *(const f32x4*)&amp[g][(m << 3) + 4];
      a0 = fmaf(aA[0], x0, a0); const float y0 = fmaf(tc, x0, -p0);
      a1 = fmaf(aA[1], x1, a1); const float y1 = fmaf(tc, x1, -p1);
      a2 = fmaf(aA[2], x2, a2); const float y2 = fmaf(tc, x2, -p2);
      a3 = fmaf(aA[3], x3, a3); const float y3 = fmaf(tc, x3, -p3);
      a0 = fmaf(aB[0], y0, a0); const float z0 = fmaf(tc, y0, -x0); p0 = y0; x0 = z0;
      a1 = fmaf(aB[1], y1, a1); const float z1 = fmaf(tc, y1, -x1); p1 = y1; x1 = z1;
      a2 = fmaf(aB[2], y2, a2); const float z2 = fmaf(tc, y2, -x2); p2 = y2; x2 = z2;
      a3 = fmaf(aB[3], y3, a3); const float z3 = fmaf(tc, y3, -x3); p3 = y3; x3 = z3;
    }
    acc = ((a0 + a1) + (a2 + a3)) * scale;
  }

  float nf = 0.f;
  {
    const f16x2* np0;
    int pe;
    if (ltid & 1) {
      np0 = (const f16x2*)C0[g];
      pe = (159 + ltid) >> 1;
    } else {
      np0 = (const f16x2*)C1[g];
      pe = (158 + ltid) >> 1;
    }
    const f16x8* ip = (const f16x8*)imp_sw[g];
#pragma unroll
    for (int k0 = 0; k0 < 8; ++k0) {
      const f16x8 i8 = ip[k0];
      const int kb = k0 << 2;
      nf = dot2f((f16x2){i8[0], i8[1]}, np0[pe - kb], nf);
      nf = dot2f((f16x2){i8[2], i8[3]}, np0[pe - kb - 1], nf);
      nf = dot2f((f16x2){i8[4], i8[5]}, np0[pe - kb - 2], nf);
      nf = dot2f((f16x2){i8[6], i8[7]}, np0[pe - kb - 3], nf);
    }
#pragma unroll
    for (int k0 = 0; k0 < 8; ++k0) {
      const f16x8 i8 = ip[8 + k0];
      const int kb = (k0 << 2) + 48;
      nf = dot2f((f16x2){i8[0], i8[1]}, np0[pe - kb], nf);
      nf = dot2f((f16x2){i8[2], i8[3]}, np0[pe - kb - 1], nf);
      nf = dot2f((f16x2){i8[4], i8[5]}, np0[pe - kb - 2], nf);
      nf = dot2f((f16x2){i8[6], i8[7]}, np0[pe - kb - 3], nf);
    }
  }

  const float v = acc + nf;
  const unsigned k = (unsigned)(KPAD_ + t * BLK_ + ltid);
  const unsigned off = ((k >> 3) << 7) + ((unsigned)b << 3) + (k & 7u);
  PH[off] = (_Float16)v;
}

// ---------------- K4: reverb Toeplitz MFMA GEMM, compact-A from IMPREV, depth-2 prefetch ----------------
static __device__ __forceinline__ f32x4 mfma_f16(f16x8 a, f16x8 b, f32x4 c) {
  return __builtin_amdgcn_mfma_f32_16x16x32_f16(a, b, c, 0, 0, 0);
}

static __device__ __forceinline__ f16x8 lfrag(const unsigned short* __restrict__ base, int byteoff) {
  const unsigned* p = (const unsigned*)((const char*)base + byteoff);
  union { unsigned u[4]; f16x8 v; } x;
  x.u[0] = p[0]; x.u[1] = p[1]; x.u[2] = p[2]; x.u[3] = p[3];
  return x.v;
}

template <int U, bool ISSUE, bool CONSUME>
__device__ __forceinline__ void conv_step(f16x8 (&Rh)[M_], f32x4 (&acc)[M_], f16x8 (&bhi2)[2],
                                          f16x8 (&nb)[2], f16x8 (&na0)[2], f16x8 (&na1)[2],
                                          const f16x8* __restrict__ ph,
                                          const unsigned short* __restrict__ abase,
                                          int& kit, int& abyte) {
  if (ISSUE) {  // loads for step U+2 (double-buffered, static parity U&1)
    kit += 64;               // +32 samples = +64 f16x8 units
    nb[U & 1] = ph[kit];
    abyte += 64;             // t -= 2  ->  A byte offset += 64
    na0[U & 1] = lfrag(abase, abyte);        // entry t
    na1[U & 1] = lfrag(abase, abyte - 32);   // entry t+1
  }
#pragma unroll
  for (int mm = 0; mm < M_; ++mm) {
    const int m = (mm + M_ - 2) & (M_ - 1);  // 14,15,0..13: doomed ring slots read first
    const int sl = (m - 2 * U) & (M_ - 1);
    acc[m] = mfma_f16(Rh[sl], bhi2[U & 1], acc[m]);
  }
  if (CONSUME) {  // install data for step U+1 (issued at step U-1, parity (U+1)&1)
    Rh[(M_ - 2 - 2 * U) & (M_ - 1)] = na0[(U + 1) & 1];
    Rh[(M_ - 1 - 2 * U) & (M_ - 1)] = na1[(U + 1) & 1];
    bhi2[(U + 1) & 1] = nb[(U + 1) & 1];
  }
}

__global__ __launch_bounds__(512) void k_mconv(const unsigned short* __restrict__ IMPREV,
                                               const f16x8* __restrict__ PH,
                                               float* __restrict__ out) {
  const int tid = threadIdx.x;
  const int s = tid >> 6, lane = tid & 63;
  int w = blockIdx.x;
  {  // bijective XCD swizzle, nwg=250 (q=31, r=2)
    const int q = NWG_ / 8, r = NWG_ % 8;
    const int xcd = w & 7, o = w >> 3;
    w = (xcd < r ? xcd * (q + 1) : r * (q + 1) + (xcd - r) * q) + o;
  }
  const int Q0 = w << 8;                    // 256 outputs per block
  const int T0 = 1022 - 128 * s;            // frag-table t at step 0, m=0 (r4-verified)

  // per-lane compact-A addressing: o(t) = 16223 - 16*t - pat; byteoff = 2*(384 + o - par)
  const int pat = (lane & 15) - ((lane >> 4) << 3);
  const int o0 = 16223 - 16 * T0 - pat;
  const int par = o0 & 1;
  const unsigned short* abase = IMPREV + (par ? ISTRIDE_ : 0);
  int abyte = 2 * (384 + o0 - par);         // byte offset of entry T0

  f16x8 Rh[M_];
#pragma unroll
  for (int m = 0; m < M_; ++m) Rh[m] = lfrag(abase, abyte - 32 * m);  // entries T0..T0+15
  f32x4 acc[M_];
#pragma unroll
  for (int m = 0; m < M_; ++m) acc[m] = (f32x4){0.f, 0.f, 0.f, 0.f};

  const f16x8* ph = PH + ((lane >> 4) << 4) + (lane & 15);
  int kit = (Q0 + 2048 * s) << 1;           // unit index (r4-verified)
  f16x8 bhi2[2], nb[2], na0[2], na1[2];
  bhi2[0] = ph[kit];
  // prologue: issue step-1 data into parity-1 buffers
  kit += 64;
  nb[1] = ph[kit];
  abyte += 64;
  na0[1] = lfrag(abase, abyte);
  na1[1] = lfrag(abase, abyte - 32);

  for (int ii = 0; ii < 7; ++ii) {          // steps 0..55
    conv_step<0, true, true>(Rh, acc, bhi2, nb, na0, na1, ph, abase, kit, abyte);
    conv_step<1, true, true>(Rh, acc, bhi2, nb, na0, na1, ph, abase, kit, abyte);
    conv_step<2, true, true>(Rh, acc, bhi2, nb, na0, na1, ph, abase, kit, abyte);
    conv_step<3, true, true>(Rh, acc, bhi2, nb, na0, na1, ph, abase, kit, abyte);
    conv_step<4, true, true>(Rh, acc, bhi2, nb, na0, na1, ph, abase, kit, abyte);
    conv_step<5, true, true>(Rh, acc, bhi2, nb, na0, na1, ph, abase, kit, abyte);
    conv_step<6, true, true>(Rh, acc, bhi2, nb, na0, na1, ph, abase, kit, abyte);
    conv_step<7, true, true>(Rh, acc, bhi2, nb, na0, na1, ph, abase, kit, abyte);
  }
  conv_step<0, true, true>(Rh, acc, bhi2, nb, na0, na1, ph, abase, kit, abyte);   // 56
  conv_step<1, true, true>(Rh, acc, bhi2, nb, na0, na1, ph, abase, kit, abyte);   // 57
  conv_step<2, true, true>(Rh, acc, bhi2, nb, na0, na1, ph, abase, kit, abyte);   // 58
  conv_step<3, true, true>(Rh, acc, bhi2, nb, na0, na1, ph, abase, kit, abyte);   // 59
  conv_step<4, true, true>(Rh, acc, bhi2, nb, na0, na1, ph, abase, kit, abyte);   // 60
  conv_step<5, true, true>(Rh, acc, bhi2, nb, na0, na1, ph, abase, kit, abyte);   // 61
  conv_step<6, false, true>(Rh, acc, bhi2, nb, na0, na1, ph, abase, kit, abyte);  // 62
  conv_step<7, false, false>(Rh, acc, bhi2, nb, na0, na1, ph, abase, kit, abyte); // 63

  // two-stage cross-wave (K-split) reduction in LDS, then coalesced stores (r4-verified)
  __shared__ f32x4 part[4][M_][64];
  if (s < 4) {
#pragma unroll
    for (int m = 0; m < M_; ++m) part[s][m][lane] = acc[m];
  }
  __syncthreads();
  if (s >= 4) {
#pragma unroll
    for (int m = 0; m < M_; ++m) part[s - 4][m][lane] += acc[m];
  }
  __syncthreads();
#pragma unroll
  for (int half = 0; half < 2; ++half) {
    const int it = tid + (half << 9);
    const int m = it >> 6, ln = it & 63;
    f32x4 v = part[0][m][ln];
    v += part[1][m][ln];
    v += part[2][m][ln];
    v += part[3][m][ln];
    const int b = ln & 15, gq = ln >> 4;
    *(f32x4*)(out + (size_t)b * N_ + Q0 + (m << 4) + (gq << 2)) = v;
  }
}

extern "C" void kernel_launch(void* const* d_in, const int* in_sizes, int n_in,
                              void* d_out, int out_size, void* d_ws, size_t ws_size,
                              hipStream_t stream) {
  const float* pitch = (const float*)d_in[0];
  const float* tamp  = (const float*)d_in[1];
  const float* harmo = (const float*)d_in[2];
  const float* nfilt = (const float*)d_in[3];
  const float* noise = (const float*)d_in[4];
  const float* rn    = (const float*)d_in[5];
  const float* dec   = (const float*)d_in[6];
  const float* wet   = (const float*)d_in[7];

  char* ws = (char*)d_ws;
  size_t off = 0;
  _Float16* PH = (_Float16*)(ws + off);     off += (size_t)KTOT_ * 16 * 2;   // 2.56 MB
  _Float16* IMPREV = (_Float16*)(ws + off); off += (size_t)2 * ISTRIDE_ * 2; // 67 KB
  double* Pv = (double*)(ws + off);         off += (size_t)B_ * T_ * 8;
  double* Xv = (double*)(ws + off);         off += (size_t)B_ * T_ * 8;
  float* out = (float*)d_out;

  k_pre<<<dim3(145), dim3(512), 0, stream>>>(pitch, rn, dec, wet, Pv, Xv, IMPREV, PH);
  k_synth<<<dim3(B_ * T_ / 2), dim3(320), 0, stream>>>(pitch, tamp, harmo, nfilt, noise, Pv, Xv, PH);
  k_mconv<<<dim3(NWG_), dim3(512), 0, stream>>>((const unsigned short*)IMPREV, (const f16x8*)PH, out);
}